// Round 2
// baseline (676.930 us; speedup 1.0000x reference)
//
#include <hip/hip_runtime.h>
#include <hip/hip_bf16.h>

#define TSEQ 4096
#define EMB 768
#define NH 12
#define DH 64
#define BT 8192  // B*T

typedef __attribute__((ext_vector_type(8))) short bf16x8;
typedef __attribute__((ext_vector_type(4))) float f32x4;

__device__ __forceinline__ f32x4 mfma16(bf16x8 a, bf16x8 b, f32x4 c) {
    return __builtin_amdgcn_mfma_f32_16x16x32_bf16(a, b, c, 0, 0, 0);
}

__device__ __forceinline__ void gload16(const void* g, void* l) {
    __builtin_amdgcn_global_load_lds((const __attribute__((address_space(1))) void*)g,
                                     (__attribute__((address_space(3))) void*)l, 16, 0, 0);
}

// ---------- conversion kernels ----------
__global__ __launch_bounds__(256) void conv_x_k(const float* __restrict__ x,
                                                __hip_bfloat16* __restrict__ xb) {
    int i = (blockIdx.x * 256 + threadIdx.x) * 4;
    float4 v = *(const float4*)(x + i);
    union { unsigned short u[4]; uint2 p; } o;
    __hip_bfloat16 t0 = __float2bfloat16(v.x); o.u[0] = *(unsigned short*)&t0;
    __hip_bfloat16 t1 = __float2bfloat16(v.y); o.u[1] = *(unsigned short*)&t1;
    __hip_bfloat16 t2 = __float2bfloat16(v.z); o.u[2] = *(unsigned short*)&t2;
    __hip_bfloat16 t3 = __float2bfloat16(v.w); o.u[3] = *(unsigned short*)&t3;
    *(uint2*)(xb + i) = o.p;
}

// transpose 768x768 fp32 (k,n) -> bf16 (n,k); z selects which weight
__global__ __launch_bounds__(256) void conv_w_k(const float* w0, const float* w1,
                                                const float* w2, const float* w3,
                                                __hip_bfloat16* o0, __hip_bfloat16* o1,
                                                __hip_bfloat16* o2, __hip_bfloat16* o3) {
    const float* w; __hip_bfloat16* o;
    switch (blockIdx.z) {
        case 0: w = w0; o = o0; break;
        case 1: w = w1; o = o1; break;
        case 2: w = w2; o = o2; break;
        default: w = w3; o = o3; break;
    }
    __shared__ float tile[32][33];
    int tx = threadIdx.x & 31, ty = threadIdx.x >> 5;  // 32 x 8
    int kb = blockIdx.y * 32, nb = blockIdx.x * 32;
    for (int i = 0; i < 32; i += 8)
        tile[ty + i][tx] = w[(size_t)(kb + ty + i) * EMB + nb + tx];
    __syncthreads();
    for (int i = 0; i < 32; i += 8)
        o[(size_t)(nb + ty + i) * EMB + kb + tx] = __float2bfloat16(tile[tx][ty + i]);
}

// ---------- GEMM body: C(M,N) = A(M,K) * Wt(N,K)^T + bias ----------
// mode 0: write bf16 (B,H,T,D)   (Q, K)
// mode 1: write bf16 (B,H,D,T)   (V transposed)
// mode 2: write fp32 row-major (M,N) with bias (final output)
__device__ __forceinline__ void gemm_body(const __hip_bfloat16* __restrict__ A,
                                          const __hip_bfloat16* __restrict__ Wt,
                                          const float* __restrict__ bias,
                                          void* __restrict__ outp, int mode) {
    __shared__ __hip_bfloat16 As[128 * 32];
    __shared__ __hip_bfloat16 Bs[128 * 32];
    const int m0 = blockIdx.x * 128, n0 = blockIdx.y * 128;
    const int tid = threadIdx.x;
    const int lane = tid & 63, l15 = lane & 15, lg = lane >> 4;
    const int wave = tid >> 6, wm = wave >> 1, wn = wave & 1;
    const int sr = tid >> 2, sc = (tid & 3) << 3;

    // per-wave-uniform LDS staging bases (lane i lands at base + i*16B)
    char* asd0 = (char*)As + wave * 1024;
    char* asd1 = (char*)As + 4096 + wave * 1024;
    char* bsd0 = (char*)Bs + wave * 1024;
    char* bsd1 = (char*)Bs + 4096 + wave * 1024;

    f32x4 acc[4][4];
    for (int i = 0; i < 4; ++i)
        for (int j = 0; j < 4; ++j) acc[i][j] = (f32x4){0.f, 0.f, 0.f, 0.f};

    for (int k0 = 0; k0 < EMB; k0 += 32) {
        __syncthreads();  // previous tile's frag reads done
        gload16(A + (size_t)(m0 + sr) * EMB + k0 + sc, asd0);
        gload16(A + (size_t)(m0 + sr + 64) * EMB + k0 + sc, asd1);
        gload16(Wt + (size_t)(n0 + sr) * EMB + k0 + sc, bsd0);
        gload16(Wt + (size_t)(n0 + sr + 64) * EMB + k0 + sc, bsd1);
        asm volatile("s_waitcnt vmcnt(0)" ::: "memory");
        __syncthreads();
        bf16x8 af[4], bfv[4];
#pragma unroll
        for (int f = 0; f < 4; ++f)
            af[f] = *(const bf16x8*)(As + (wm * 64 + f * 16 + l15) * 32 + lg * 8);
#pragma unroll
        for (int f = 0; f < 4; ++f)
            bfv[f] = *(const bf16x8*)(Bs + (wn * 64 + f * 16 + l15) * 32 + lg * 8);
        __builtin_amdgcn_s_setprio(1);
#pragma unroll
        for (int i = 0; i < 4; ++i)
#pragma unroll
            for (int j = 0; j < 4; ++j)
                acc[i][j] = mfma16(af[i], bfv[j], acc[i][j]);
        __builtin_amdgcn_s_setprio(0);
    }

#pragma unroll
    for (int i = 0; i < 4; ++i) {
#pragma unroll
        for (int j = 0; j < 4; ++j) {
            const int n = n0 + wn * 64 + j * 16 + l15;
            const float bv = bias[n];
            const int mbase = m0 + wm * 64 + i * 16 + lg * 4;
#pragma unroll
            for (int r = 0; r < 4; ++r) {
                const int m = mbase + r;
                const float val = acc[i][j][r] + bv;
                if (mode == 2) {
                    ((float*)outp)[(size_t)m * EMB + n] = val;
                } else {
                    const int b = m >> 12, t = m & (TSEQ - 1);
                    const int h = n >> 6, d = n & 63;
                    size_t addr;
                    if (mode == 0) addr = ((size_t)(b * NH + h) * TSEQ + t) * DH + d;
                    else           addr = ((size_t)(b * NH + h) * DH + d) * TSEQ + t;
                    ((__hip_bfloat16*)outp)[addr] = __float2bfloat16(val);
                }
            }
        }
    }
}

__global__ __launch_bounds__(256) void qkv_k(const __hip_bfloat16* __restrict__ xb,
                                             const __hip_bfloat16* __restrict__ wqT,
                                             const __hip_bfloat16* __restrict__ wkT,
                                             const __hip_bfloat16* __restrict__ wvT,
                                             const float* __restrict__ bq,
                                             const float* __restrict__ bk,
                                             const float* __restrict__ bv,
                                             __hip_bfloat16* __restrict__ qo,
                                             __hip_bfloat16* __restrict__ ko,
                                             __hip_bfloat16* __restrict__ vo) {
    const __hip_bfloat16* Wt; const float* bias; void* o; int mode;
    switch (blockIdx.z) {
        case 0:  Wt = wqT; bias = bq; o = qo; mode = 0; break;
        case 1:  Wt = wkT; bias = bk; o = ko; mode = 0; break;
        default: Wt = wvT; bias = bv; o = vo; mode = 1; break;
    }
    gemm_body(xb, Wt, bias, o, mode);
}

__global__ __launch_bounds__(256) void oproj_k(const __hip_bfloat16* __restrict__ abf,
                                               const __hip_bfloat16* __restrict__ woT,
                                               const float* __restrict__ bo,
                                               float* __restrict__ out) {
    gemm_body(abf, woT, bo, out, 2);
}

// ---------- flash attention ----------
// Q,K: (B,H,T,D) bf16.  V: (B,H,D,T) bf16.  out ab: (B,T,E) bf16.
// Block = one 32-row q-tile; 4 waves split s-blocks stride-4 (private m/l/O
// partials), then in-block LDS combine. P bounce via XOR-swizzled 128B rows.
__global__ __launch_bounds__(256, 4) void attn_k(const __hip_bfloat16* __restrict__ qb,
                                                 const __hip_bfloat16* __restrict__ kb,
                                                 const __hip_bfloat16* __restrict__ vt,
                                                 __hip_bfloat16* __restrict__ ab) {
    // per wave: [0..2047] fp32 = O partial 32x64 (first 4KB doubles as P buffer
    // during the loop), [2048..2079] m, [2080..2111] l
    __shared__ float smem[4][2112];
    const int bh = blockIdx.y;
    const int lane = threadIdx.x & 63, l15 = lane & 15, lg = lane >> 4;
    const int wave = threadIdx.x >> 6;
    const int q0 = blockIdx.x * 32;
    const __hip_bfloat16* Qh = qb + (size_t)bh * TSEQ * DH;
    const __hip_bfloat16* Kh = kb + (size_t)bh * TSEQ * DH;
    const __hip_bfloat16* Vh = vt + (size_t)bh * DH * TSEQ;
    char* Pb = (char*)smem[wave];
    float* osm = smem[wave];
    const float c = 0.125f * 1.44269504089f;  // scale * log2(e)
    const int swz = (l15 & 7) << 4;

    bf16x8 qf[2][2];
#pragma unroll
    for (int qt = 0; qt < 2; ++qt)
#pragma unroll
        for (int ks = 0; ks < 2; ++ks)
            qf[qt][ks] = *(const bf16x8*)(Qh + (size_t)(q0 + qt * 16 + l15) * DH + ks * 32 + lg * 8);

    f32x4 o[2][4];
    for (int qt = 0; qt < 2; ++qt)
        for (int dt = 0; dt < 4; ++dt) o[qt][dt] = (f32x4){0.f, 0.f, 0.f, 0.f};
    float mrow[2] = {-1e30f, -1e30f};
    float lrow[2] = {0.f, 0.f};

    const int nsb = (q0 >> 6) + 1;
    for (int sb = wave; sb < nsb; sb += 4) {
        const int s0 = sb << 6;
        const bool maskneed = (s0 + 63 > q0);
        bf16x8 kf[4][2], vf[4][2];
#pragma unroll
        for (int st = 0; st < 4; ++st)
#pragma unroll
            for (int ks = 0; ks < 2; ++ks)
                kf[st][ks] = *(const bf16x8*)(Kh + (size_t)(s0 + st * 16 + l15) * DH + ks * 32 + lg * 8);
#pragma unroll
        for (int dt = 0; dt < 4; ++dt)
#pragma unroll
            for (int ks = 0; ks < 2; ++ks)
                vf[dt][ks] = *(const bf16x8*)(Vh + (size_t)(dt * 16 + l15) * TSEQ + s0 + ks * 32 + lg * 8);

#pragma unroll
        for (int qt = 0; qt < 2; ++qt) {
            // S^T tiles: D[row = s-in-tile, col = q = l15]
            f32x4 sa[4];
            __builtin_amdgcn_s_setprio(1);
#pragma unroll
            for (int st = 0; st < 4; ++st) {
                f32x4 z = (f32x4){0.f, 0.f, 0.f, 0.f};
                z = mfma16(kf[st][0], qf[qt][0], z);
                z = mfma16(kf[st][1], qf[qt][1], z);
                sa[st] = z;
            }
            __builtin_amdgcn_s_setprio(0);
            const int q = q0 + qt * 16 + l15;
            if (maskneed) {
#pragma unroll
                for (int st = 0; st < 4; ++st)
#pragma unroll
                    for (int r = 0; r < 4; ++r)
                        if (s0 + st * 16 + lg * 4 + r > q) sa[st][r] = -INFINITY;
            }
            float mx = -1e30f;
#pragma unroll
            for (int st = 0; st < 4; ++st)
#pragma unroll
                for (int r = 0; r < 4; ++r) mx = fmaxf(mx, sa[st][r]);
            mx = fmaxf(mx, __shfl_xor(mx, 16));
            mx = fmaxf(mx, __shfl_xor(mx, 32));
            const float mnew = fmaxf(mrow[qt], mx);

            float sum = 0.f;
#pragma unroll
            for (int st = 0; st < 4; ++st) {
                union { unsigned short u[4]; uint2 v; } pk;
#pragma unroll
                for (int r = 0; r < 4; ++r) {
                    const float p = exp2f((sa[st][r] - mnew) * c);
                    sum += p;
                    __hip_bfloat16 hb = __float2bfloat16(p);
                    pk.u[r] = *(unsigned short*)&hb;
                }
                *(uint2*)(Pb + qt * 2048 + l15 * 128 + ((st * 32 + lg * 8) ^ swz)) = pk.v;
            }
            sum += __shfl_xor(sum, 16);
            sum += __shfl_xor(sum, 32);
            const float rescale = exp2f((mrow[qt] - mnew) * c);
            lrow[qt] = lrow[qt] * rescale + sum;
            mrow[qt] = mnew;

            float fr[4];
#pragma unroll
            for (int r = 0; r < 4; ++r) fr[r] = __shfl(rescale, lg * 4 + r);
#pragma unroll
            for (int dt = 0; dt < 4; ++dt) {
                f32x4 ov = o[qt][dt];
#pragma unroll
                for (int r = 0; r < 4; ++r) ov[r] *= fr[r];
                o[qt][dt] = ov;
            }

            asm volatile("s_waitcnt lgkmcnt(0)" ::: "memory");  // P writes visible wave-wide
            __builtin_amdgcn_s_setprio(1);
#pragma unroll
            for (int ks = 0; ks < 2; ++ks) {
                bf16x8 pf = *(const bf16x8*)(Pb + qt * 2048 + l15 * 128 + ((ks * 64 + lg * 16) ^ swz));
#pragma unroll
                for (int dt = 0; dt < 4; ++dt)
                    o[qt][dt] = mfma16(pf, vf[dt][ks], o[qt][dt]);
            }
            __builtin_amdgcn_s_setprio(0);
        }
    }

    // ---- write per-wave partial (O unnormalized, m, l) to this wave's LDS ----
#pragma unroll
    for (int qt = 0; qt < 2; ++qt) {
#pragma unroll
        for (int dt = 0; dt < 4; ++dt)
#pragma unroll
            for (int r = 0; r < 4; ++r)
                osm[(qt * 16 + lg * 4 + r) * 64 + dt * 16 + l15] = o[qt][dt][r];
        if (lg == 0) {
            osm[2048 + qt * 16 + l15] = mrow[qt];
            osm[2080 + qt * 16 + l15] = lrow[qt];
        }
    }
    __syncthreads();

    // ---- combine 4 partials; wave handles q-rows [wave*8, wave*8+8) ----
    const int qr = wave * 8 + (lane >> 3);   // local q row 0..31
    const int d0 = (lane & 7) * 8;           // 8 d-columns per lane
    float m4[4];
    float mstar = -1e30f;
#pragma unroll
    for (int w = 0; w < 4; ++w) { m4[w] = smem[w][2048 + qr]; mstar = fmaxf(mstar, m4[w]); }
    float fw[4];
    float lstar = 0.f;
#pragma unroll
    for (int w = 0; w < 4; ++w) {
        fw[w] = exp2f((m4[w] - mstar) * c);
        lstar += fw[w] * smem[w][2080 + qr];
    }
    const float inv = 1.0f / lstar;
    float accv[8] = {0.f, 0.f, 0.f, 0.f, 0.f, 0.f, 0.f, 0.f};
#pragma unroll
    for (int w = 0; w < 4; ++w) {
        f32x4 a = *(const f32x4*)(smem[w] + qr * 64 + d0);
        f32x4 bqv = *(const f32x4*)(smem[w] + qr * 64 + d0 + 4);
#pragma unroll
        for (int j = 0; j < 4; ++j) { accv[j] += fw[w] * a[j]; accv[4 + j] += fw[w] * bqv[j]; }
    }
    const int b = bh / NH, h = bh % NH;
    union { unsigned short u[8]; uint4 v; } ob;
#pragma unroll
    for (int j = 0; j < 8; ++j) {
        __hip_bfloat16 hb = __float2bfloat16(accv[j] * inv);
        ob.u[j] = *(unsigned short*)&hb;
    }
    *(uint4*)(ab + ((size_t)b * TSEQ + q0 + qr) * EMB + h * DH + d0) = ob.v;
}

extern "C" void kernel_launch(void* const* d_in, const int* in_sizes, int n_in,
                              void* d_out, int out_size, void* d_ws, size_t ws_size,
                              hipStream_t stream) {
    (void)in_sizes; (void)n_in; (void)out_size; (void)ws_size;
    const float* x  = (const float*)d_in[0];
    const float* wq = (const float*)d_in[1];
    const float* bq = (const float*)d_in[2];
    const float* wk = (const float*)d_in[3];
    const float* bk = (const float*)d_in[4];
    const float* wv = (const float*)d_in[5];
    const float* bv = (const float*)d_in[6];
    const float* wo = (const float*)d_in[7];
    const float* bo = (const float*)d_in[8];
    float* out = (float*)d_out;

    char* ws = (char*)d_ws;
    size_t off = 0;
    auto alloc = [&](size_t bytes) {
        char* p = ws + off;
        off += (bytes + 255) & ~(size_t)255;
        return p;
    };
    __hip_bfloat16* xb  = (__hip_bfloat16*)alloc((size_t)BT * EMB * 2);
    __hip_bfloat16* qbf = (__hip_bfloat16*)alloc((size_t)BT * EMB * 2);
    __hip_bfloat16* kbf = (__hip_bfloat16*)alloc((size_t)BT * EMB * 2);
    __hip_bfloat16* vtb = (__hip_bfloat16*)alloc((size_t)BT * EMB * 2);
    __hip_bfloat16* abf = (__hip_bfloat16*)alloc((size_t)BT * EMB * 2);
    __hip_bfloat16* wqT = (__hip_bfloat16*)alloc((size_t)EMB * EMB * 2);
    __hip_bfloat16* wkT = (__hip_bfloat16*)alloc((size_t)EMB * EMB * 2);
    __hip_bfloat16* wvT = (__hip_bfloat16*)alloc((size_t)EMB * EMB * 2);
    __hip_bfloat16* woT = (__hip_bfloat16*)alloc((size_t)EMB * EMB * 2);

    conv_x_k<<<BT * EMB / 1024, 256, 0, stream>>>(x, xb);
    conv_w_k<<<dim3(24, 24, 4), 256, 0, stream>>>(wq, wk, wv, wo, wqT, wkT, wvT, woT);
    qkv_k<<<dim3(64, 6, 3), 256, 0, stream>>>(xb, wqT, wkT, wvT, bq, bk, bv, qbf, kbf, vtb);
    attn_k<<<dim3(TSEQ / 32, 24), 256, 0, stream>>>(qbf, kbf, vtb, abf);
    oproj_k<<<dim3(64, 6), 256, 0, stream>>>(abf, woT, bo, out);
}

// Round 3
// 446.388 us; speedup vs baseline: 1.5165x; 1.5165x over previous
//
#include <hip/hip_runtime.h>
#include <hip/hip_bf16.h>

#define TSEQ 4096
#define EMB 768
#define NH 12
#define DH 64
#define BT 8192  // B*T

typedef __attribute__((ext_vector_type(8))) short bf16x8;
typedef __attribute__((ext_vector_type(4))) float f32x4;

__device__ __forceinline__ f32x4 mfma16(bf16x8 a, bf16x8 b, f32x4 c) {
    return __builtin_amdgcn_mfma_f32_16x16x32_bf16(a, b, c, 0, 0, 0);
}

__device__ __forceinline__ void gload16(const void* g, void* l) {
    __builtin_amdgcn_global_load_lds((const __attribute__((address_space(1))) void*)g,
                                     (__attribute__((address_space(3))) void*)l, 16, 0, 0);
}

// ---------- conversion kernels ----------
__global__ __launch_bounds__(256) void conv_x_k(const float* __restrict__ x,
                                                __hip_bfloat16* __restrict__ xb) {
    int i = (blockIdx.x * 256 + threadIdx.x) * 4;
    float4 v = *(const float4*)(x + i);
    union { unsigned short u[4]; uint2 p; } o;
    __hip_bfloat16 t0 = __float2bfloat16(v.x); o.u[0] = *(unsigned short*)&t0;
    __hip_bfloat16 t1 = __float2bfloat16(v.y); o.u[1] = *(unsigned short*)&t1;
    __hip_bfloat16 t2 = __float2bfloat16(v.z); o.u[2] = *(unsigned short*)&t2;
    __hip_bfloat16 t3 = __float2bfloat16(v.w); o.u[3] = *(unsigned short*)&t3;
    *(uint2*)(xb + i) = o.p;
}

// transpose 768x768 fp32 (k,n) -> bf16 (n,k); z selects which weight
__global__ __launch_bounds__(256) void conv_w_k(const float* w0, const float* w1,
                                                const float* w2, const float* w3,
                                                __hip_bfloat16* o0, __hip_bfloat16* o1,
                                                __hip_bfloat16* o2, __hip_bfloat16* o3) {
    const float* w; __hip_bfloat16* o;
    switch (blockIdx.z) {
        case 0: w = w0; o = o0; break;
        case 1: w = w1; o = o1; break;
        case 2: w = w2; o = o2; break;
        default: w = w3; o = o3; break;
    }
    __shared__ float tile[32][33];
    int tx = threadIdx.x & 31, ty = threadIdx.x >> 5;  // 32 x 8
    int kb = blockIdx.y * 32, nb = blockIdx.x * 32;
    for (int i = 0; i < 32; i += 8)
        tile[ty + i][tx] = w[(size_t)(kb + ty + i) * EMB + nb + tx];
    __syncthreads();
    for (int i = 0; i < 32; i += 8)
        o[(size_t)(nb + ty + i) * EMB + kb + tx] = __float2bfloat16(tile[tx][ty + i]);
}

// ---------- GEMM body: C(M,N) = scale * (A(M,K) * Wt(N,K)^T + bias) ----------
// mode 0: write bf16 (B,H,T,D)   (Q, K)
// mode 1: write bf16 (B,H,D,T)   (V transposed)
// mode 2: write fp32 row-major (M,N) with bias (final output)
__device__ __forceinline__ void gemm_body(const __hip_bfloat16* __restrict__ A,
                                          const __hip_bfloat16* __restrict__ Wt,
                                          const float* __restrict__ bias,
                                          void* __restrict__ outp, int mode, float scale) {
    __shared__ __hip_bfloat16 As[128 * 32];
    __shared__ __hip_bfloat16 Bs[128 * 32];
    const int m0 = blockIdx.x * 128, n0 = blockIdx.y * 128;
    const int tid = threadIdx.x;
    const int lane = tid & 63, l15 = lane & 15, lg = lane >> 4;
    const int wave = tid >> 6, wm = wave >> 1, wn = wave & 1;
    const int sr = tid >> 2, sc = (tid & 3) << 3;

    // per-wave-uniform LDS staging bases (lane i lands at base + i*16B)
    char* asd0 = (char*)As + wave * 1024;
    char* asd1 = (char*)As + 4096 + wave * 1024;
    char* bsd0 = (char*)Bs + wave * 1024;
    char* bsd1 = (char*)Bs + 4096 + wave * 1024;

    f32x4 acc[4][4];
    for (int i = 0; i < 4; ++i)
        for (int j = 0; j < 4; ++j) acc[i][j] = (f32x4){0.f, 0.f, 0.f, 0.f};

    for (int k0 = 0; k0 < EMB; k0 += 32) {
        __syncthreads();  // previous tile's frag reads done
        gload16(A + (size_t)(m0 + sr) * EMB + k0 + sc, asd0);
        gload16(A + (size_t)(m0 + sr + 64) * EMB + k0 + sc, asd1);
        gload16(Wt + (size_t)(n0 + sr) * EMB + k0 + sc, bsd0);
        gload16(Wt + (size_t)(n0 + sr + 64) * EMB + k0 + sc, bsd1);
        asm volatile("s_waitcnt vmcnt(0)" ::: "memory");
        __syncthreads();
        bf16x8 af[4], bfv[4];
#pragma unroll
        for (int f = 0; f < 4; ++f)
            af[f] = *(const bf16x8*)(As + (wm * 64 + f * 16 + l15) * 32 + lg * 8);
#pragma unroll
        for (int f = 0; f < 4; ++f)
            bfv[f] = *(const bf16x8*)(Bs + (wn * 64 + f * 16 + l15) * 32 + lg * 8);
        __builtin_amdgcn_s_setprio(1);
#pragma unroll
        for (int i = 0; i < 4; ++i)
#pragma unroll
            for (int j = 0; j < 4; ++j)
                acc[i][j] = mfma16(af[i], bfv[j], acc[i][j]);
        __builtin_amdgcn_s_setprio(0);
    }

#pragma unroll
    for (int i = 0; i < 4; ++i) {
#pragma unroll
        for (int j = 0; j < 4; ++j) {
            const int n = n0 + wn * 64 + j * 16 + l15;
            const float bv = bias[n];
            const int mbase = m0 + wm * 64 + i * 16 + lg * 4;
#pragma unroll
            for (int r = 0; r < 4; ++r) {
                const int m = mbase + r;
                const float val = (acc[i][j][r] + bv) * scale;
                if (mode == 2) {
                    ((float*)outp)[(size_t)m * EMB + n] = val;
                } else {
                    const int b = m >> 12, t = m & (TSEQ - 1);
                    const int h = n >> 6, d = n & 63;
                    size_t addr;
                    if (mode == 0) addr = ((size_t)(b * NH + h) * TSEQ + t) * DH + d;
                    else           addr = ((size_t)(b * NH + h) * DH + d) * TSEQ + t;
                    ((__hip_bfloat16*)outp)[addr] = __float2bfloat16(val);
                }
            }
        }
    }
}

__global__ __launch_bounds__(256) void qkv_k(const __hip_bfloat16* __restrict__ xb,
                                             const __hip_bfloat16* __restrict__ wqT,
                                             const __hip_bfloat16* __restrict__ wkT,
                                             const __hip_bfloat16* __restrict__ wvT,
                                             const float* __restrict__ bq,
                                             const float* __restrict__ bk,
                                             const float* __restrict__ bv,
                                             __hip_bfloat16* __restrict__ qo,
                                             __hip_bfloat16* __restrict__ ko,
                                             __hip_bfloat16* __restrict__ vo) {
    const __hip_bfloat16* Wt; const float* bias; void* o; int mode; float scale;
    const float cq = 0.125f * 1.44269504089f;  // softmax scale * log2(e), folded into Q
    switch (blockIdx.z) {
        case 0:  Wt = wqT; bias = bq; o = qo; mode = 0; scale = cq;  break;
        case 1:  Wt = wkT; bias = bk; o = ko; mode = 0; scale = 1.f; break;
        default: Wt = wvT; bias = bv; o = vo; mode = 1; scale = 1.f; break;
    }
    gemm_body(xb, Wt, bias, o, mode, scale);
}

__global__ __launch_bounds__(256) void oproj_k(const __hip_bfloat16* __restrict__ abf,
                                               const __hip_bfloat16* __restrict__ woT,
                                               const float* __restrict__ bo,
                                               float* __restrict__ out) {
    gemm_body(abf, woT, bo, out, 2, 1.f);
}

// ---------- flash attention ----------
// Q (pre-scaled by 0.125*log2e), K: (B,H,T,D) bf16. V: (B,H,D,T) bf16.
// out ab: (B,T,E) bf16.
// Block = 64 q-rows (4 waves x 16 rows), folded tile pair (i, 63-i) for
// uniform work: every wave does exactly 65 s-blocks. Grid 768 = 3 blocks/CU.
// Head-clustered XCD mapping: all blocks of a head on one XCD (K/V L2-resident).
__global__ __launch_bounds__(256) void attn_k(const __hip_bfloat16* __restrict__ qb,
                                              const __hip_bfloat16* __restrict__ kb,
                                              const __hip_bfloat16* __restrict__ vt,
                                              __hip_bfloat16* __restrict__ ab) {
    __shared__ char pbuf[4][2048];  // per-wave P bounce, 16 rows x 128B, XOR-swizzled
    const int lane = threadIdx.x & 63, l15 = lane & 15, lg = lane >> 4;
    const int wave = threadIdx.x >> 6;
    const int bid = blockIdx.x;
    const int xcd = bid & 7, slot = bid >> 3;
    const int pair = slot & 31, hgrp = slot >> 5;
    const int bh = xcd + hgrp * 8;           // head h's 32 blocks share bid%8 -> same XCD
    const __hip_bfloat16* Qh = qb + (size_t)bh * TSEQ * DH;
    const __hip_bfloat16* Kh = kb + (size_t)bh * TSEQ * DH;
    const __hip_bfloat16* Vh = vt + (size_t)bh * DH * TSEQ;
    char* Pb = pbuf[wave];
    const int swz = (l15 & 7) << 4;
    const int b = bh / NH, h = bh % NH;

    for (int tt = 0; tt < 2; ++tt) {
        const int tile = tt ? (63 - pair) : pair;
        const int q0 = tile * 64 + wave * 16;

        bf16x8 qf[2];
#pragma unroll
        for (int ks = 0; ks < 2; ++ks)
            qf[ks] = *(const bf16x8*)(Qh + (size_t)(q0 + l15) * DH + ks * 32 + lg * 8);

        f32x4 o[4];
#pragma unroll
        for (int dt = 0; dt < 4; ++dt) o[dt] = (f32x4){0.f, 0.f, 0.f, 0.f};
        float m = -1e30f, lsum = 0.f;

        const int nsb = tile + 1;
        for (int sb = 0; sb < nsb; ++sb) {
            const int s0 = sb << 6;
            const bool maskneed = (s0 + 63 > q0);
            bf16x8 kf[4][2], vf[4][2];
#pragma unroll
            for (int st = 0; st < 4; ++st)
#pragma unroll
                for (int ks = 0; ks < 2; ++ks)
                    kf[st][ks] = *(const bf16x8*)(Kh + (size_t)(s0 + st * 16 + l15) * DH + ks * 32 + lg * 8);
#pragma unroll
            for (int dt = 0; dt < 4; ++dt)
#pragma unroll
                for (int ks = 0; ks < 2; ++ks)
                    vf[dt][ks] = *(const bf16x8*)(Vh + (size_t)(dt * 16 + l15) * TSEQ + s0 + ks * 32 + lg * 8);

            // S^T tiles: D[row = s-in-tile, col = q = l15], log2-domain (Q pre-scaled)
            f32x4 sa[4];
            __builtin_amdgcn_s_setprio(1);
#pragma unroll
            for (int st = 0; st < 4; ++st) {
                f32x4 z = (f32x4){0.f, 0.f, 0.f, 0.f};
                z = mfma16(kf[st][0], qf[0], z);
                z = mfma16(kf[st][1], qf[1], z);
                sa[st] = z;
            }
            __builtin_amdgcn_s_setprio(0);
            const int q = q0 + l15;
            if (maskneed) {
#pragma unroll
                for (int st = 0; st < 4; ++st)
#pragma unroll
                    for (int r = 0; r < 4; ++r)
                        if (s0 + st * 16 + lg * 4 + r > q) sa[st][r] = -INFINITY;
            }
            float mx = -1e30f;
#pragma unroll
            for (int st = 0; st < 4; ++st)
#pragma unroll
                for (int r = 0; r < 4; ++r) mx = fmaxf(mx, sa[st][r]);
            mx = fmaxf(mx, __shfl_xor(mx, 16));
            mx = fmaxf(mx, __shfl_xor(mx, 32));

            // defer-max (T13): skip rescale when column max grew <= 8 (log2 units)
            float mnew = m;
            const bool grow = !__all(mx <= m + 8.0f);
            if (grow) {
                mnew = fmaxf(m, mx);
                const float rescale = exp2f(m - mnew);
                m = mnew;
                float fr[4];
#pragma unroll
                for (int r = 0; r < 4; ++r) fr[r] = __shfl(rescale, lg * 4 + r);
#pragma unroll
                for (int dt = 0; dt < 4; ++dt) {
                    f32x4 ov = o[dt];
#pragma unroll
                    for (int r = 0; r < 4; ++r) ov[r] *= fr[r];
                    o[dt] = ov;
                }
                lsum *= rescale;
            }

            float sum = 0.f;
#pragma unroll
            for (int st = 0; st < 4; ++st) {
                union { unsigned short u[4]; uint2 v; } pk;
#pragma unroll
                for (int r = 0; r < 4; ++r) {
                    const float p = exp2f(sa[st][r] - mnew);
                    sum += p;
                    __hip_bfloat16 hb = __float2bfloat16(p);
                    pk.u[r] = *(unsigned short*)&hb;
                }
                *(uint2*)(Pb + l15 * 128 + ((st * 32 + lg * 8) ^ swz)) = pk.v;
            }
            sum += __shfl_xor(sum, 16);
            sum += __shfl_xor(sum, 32);
            lsum += sum;

            asm volatile("s_waitcnt lgkmcnt(0)" ::: "memory");  // P writes visible wave-wide
            __builtin_amdgcn_s_setprio(1);
#pragma unroll
            for (int ks = 0; ks < 2; ++ks) {
                bf16x8 pf = *(const bf16x8*)(Pb + l15 * 128 + ((ks * 64 + lg * 16) ^ swz));
#pragma unroll
                for (int dt = 0; dt < 4; ++dt)
                    o[dt] = mfma16(pf, vf[dt][ks], o[dt]);
            }
            __builtin_amdgcn_s_setprio(0);
            asm volatile("s_waitcnt lgkmcnt(0)" ::: "memory");  // P reads done before next sb
        }

        const float linv = 1.0f / lsum;
        float lr[4];
#pragma unroll
        for (int r = 0; r < 4; ++r) lr[r] = __shfl(linv, lg * 4 + r);
#pragma unroll
        for (int r = 0; r < 4; ++r) {
            const int qrow = q0 + lg * 4 + r;
            const size_t rowbase = ((size_t)b * TSEQ + qrow) * EMB + h * DH;
#pragma unroll
            for (int dt = 0; dt < 4; ++dt)
                ab[rowbase + dt * 16 + l15] = __float2bfloat16(o[dt][r] * lr[r]);
        }
    }
}

extern "C" void kernel_launch(void* const* d_in, const int* in_sizes, int n_in,
                              void* d_out, int out_size, void* d_ws, size_t ws_size,
                              hipStream_t stream) {
    (void)in_sizes; (void)n_in; (void)out_size; (void)ws_size;
    const float* x  = (const float*)d_in[0];
    const float* wq = (const float*)d_in[1];
    const float* bq = (const float*)d_in[2];
    const float* wk = (const float*)d_in[3];
    const float* bk = (const float*)d_in[4];
    const float* wv = (const float*)d_in[5];
    const float* bv = (const float*)d_in[6];
    const float* wo = (const float*)d_in[7];
    const float* bo = (const float*)d_in[8];
    float* out = (float*)d_out;

    char* ws = (char*)d_ws;
    size_t off = 0;
    auto alloc = [&](size_t bytes) {
        char* p = ws + off;
        off += (bytes + 255) & ~(size_t)255;
        return p;
    };
    __hip_bfloat16* xb  = (__hip_bfloat16*)alloc((size_t)BT * EMB * 2);
    __hip_bfloat16* qbf = (__hip_bfloat16*)alloc((size_t)BT * EMB * 2);
    __hip_bfloat16* kbf = (__hip_bfloat16*)alloc((size_t)BT * EMB * 2);
    __hip_bfloat16* vtb = (__hip_bfloat16*)alloc((size_t)BT * EMB * 2);
    __hip_bfloat16* abf = (__hip_bfloat16*)alloc((size_t)BT * EMB * 2);
    __hip_bfloat16* wqT = (__hip_bfloat16*)alloc((size_t)EMB * EMB * 2);
    __hip_bfloat16* wkT = (__hip_bfloat16*)alloc((size_t)EMB * EMB * 2);
    __hip_bfloat16* wvT = (__hip_bfloat16*)alloc((size_t)EMB * EMB * 2);
    __hip_bfloat16* woT = (__hip_bfloat16*)alloc((size_t)EMB * EMB * 2);

    conv_x_k<<<BT * EMB / 1024, 256, 0, stream>>>(x, xb);
    conv_w_k<<<dim3(24, 24, 4), 256, 0, stream>>>(wq, wk, wv, wo, wqT, wkT, wvT, woT);
    qkv_k<<<dim3(64, 6, 3), 256, 0, stream>>>(xb, wqT, wkT, wvT, bq, bk, bv, qbf, kbf, vtb);
    attn_k<<<768, 256, 0, stream>>>(qbf, kbf, vtb, abf);
    oproj_k<<<dim3(64, 6), 256, 0, stream>>>(abf, woT, bo, out);
}

// Round 4
// 218.099 us; speedup vs baseline: 3.1038x; 2.0467x over previous
//
#include <hip/hip_runtime.h>
#include <hip/hip_bf16.h>

#define TSEQ 4096
#define EMB 768
#define NH 12
#define DH 64
#define BT 8192  // B*T

typedef __attribute__((ext_vector_type(8))) short bf16x8;
typedef __attribute__((ext_vector_type(4))) float f32x4;

#define FENCE() asm volatile("" ::: "memory")

__device__ __forceinline__ f32x4 mfma16(bf16x8 a, bf16x8 b, f32x4 c) {
    return __builtin_amdgcn_mfma_f32_16x16x32_bf16(a, b, c, 0, 0, 0);
}

__device__ __forceinline__ void gload16(const void* g, void* l) {
    __builtin_amdgcn_global_load_lds((const __attribute__((address_space(1))) void*)g,
                                     (__attribute__((address_space(3))) void*)l, 16, 0, 0);
}

// ---------- conversion kernels ----------
__global__ __launch_bounds__(256) void conv_x_k(const float* __restrict__ x,
                                                __hip_bfloat16* __restrict__ xb) {
    int i = (blockIdx.x * 256 + threadIdx.x) * 4;
    float4 v = *(const float4*)(x + i);
    union { unsigned short u[4]; uint2 p; } o;
    __hip_bfloat16 t0 = __float2bfloat16(v.x); o.u[0] = *(unsigned short*)&t0;
    __hip_bfloat16 t1 = __float2bfloat16(v.y); o.u[1] = *(unsigned short*)&t1;
    __hip_bfloat16 t2 = __float2bfloat16(v.z); o.u[2] = *(unsigned short*)&t2;
    __hip_bfloat16 t3 = __float2bfloat16(v.w); o.u[3] = *(unsigned short*)&t3;
    *(uint2*)(xb + i) = o.p;
}

// transpose 768x768 fp32 (k,n) -> bf16 (n,k); z selects which weight
__global__ __launch_bounds__(256) void conv_w_k(const float* w0, const float* w1,
                                                const float* w2, const float* w3,
                                                __hip_bfloat16* o0, __hip_bfloat16* o1,
                                                __hip_bfloat16* o2, __hip_bfloat16* o3) {
    const float* w; __hip_bfloat16* o;
    switch (blockIdx.z) {
        case 0: w = w0; o = o0; break;
        case 1: w = w1; o = o1; break;
        case 2: w = w2; o = o2; break;
        default: w = w3; o = o3; break;
    }
    __shared__ float tile[32][33];
    int tx = threadIdx.x & 31, ty = threadIdx.x >> 5;  // 32 x 8
    int kb = blockIdx.y * 32, nb = blockIdx.x * 32;
    for (int i = 0; i < 32; i += 8)
        tile[ty + i][tx] = w[(size_t)(kb + ty + i) * EMB + nb + tx];
    __syncthreads();
    for (int i = 0; i < 32; i += 8)
        o[(size_t)(nb + ty + i) * EMB + kb + tx] = __float2bfloat16(tile[tx][ty + i]);
}

// ---------- GEMM body: C(M,N) = scale * (A(M,K) * Wt(N,K)^T + bias) ----------
// LDS tile: 64 "rows" x 128B; logical (m,k): m = lrow + 64*(colbyte>>6),
// kbyte = colbyte&63. XOR-swizzled (byte ^= (lrow&7)<<4), staged with
// inverse-swizzled global source (gload_lds writes linearly).
// mode 0: write bf16 (B,H,T,D); mode 1: bf16 (B,H,D,T); mode 2: fp32 (M,N).
__device__ __forceinline__ void gemm_body(const __hip_bfloat16* __restrict__ A,
                                          const __hip_bfloat16* __restrict__ Wt,
                                          const float* __restrict__ bias,
                                          void* __restrict__ outp, int mode, float scale) {
    __shared__ alignas(16) char As[2][8192];
    __shared__ alignas(16) char Bs[2][8192];
    const int m0 = blockIdx.x * 128, n0 = blockIdx.y * 128;
    const int tid = threadIdx.x;
    const int lane = tid & 63, l15 = lane & 15, lg = lane >> 4;
    const int wave = tid >> 6, wm = wave >> 1, wn = wave & 1;
    const int swz = (l15 & 7) << 4;

    // staging geometry: chunk c in {0,1}: linear p = c*4096 + tid*16
    // lrow = p>>7, w = p&127, w' = w ^ ((lrow&7)<<4)
    int mrow_[2]; int kelem_[2];
#pragma unroll
    for (int c = 0; c < 2; ++c) {
        int p = c * 4096 + tid * 16;
        int lrow = p >> 7, w = p & 127;
        int wp = w ^ ((lrow & 7) << 4);
        mrow_[c] = lrow + ((wp >> 6) & 1) * 64;
        kelem_[c] = (wp & 63) >> 1;
    }

    f32x4 acc[4][4];
    for (int i = 0; i < 4; ++i)
        for (int j = 0; j < 4; ++j) acc[i][j] = (f32x4){0.f, 0.f, 0.f, 0.f};

    auto stage = [&](int buf, int k0) {
#pragma unroll
        for (int c = 0; c < 2; ++c)
            gload16(A + (size_t)(m0 + mrow_[c]) * EMB + k0 + kelem_[c],
                    As[buf] + c * 4096 + wave * 1024);
#pragma unroll
        for (int c = 0; c < 2; ++c)
            gload16(Wt + (size_t)(n0 + mrow_[c]) * EMB + k0 + kelem_[c],
                    Bs[buf] + c * 4096 + wave * 1024);
    };

    stage(0, 0);
    const int NK = EMB / 32;
    for (int ks = 0; ks < NK; ++ks) {
        const int cur = ks & 1;
        const bool pre = (ks + 1 < NK);
        if (pre) stage(cur ^ 1, (ks + 1) * 32);
        if (pre) asm volatile("s_waitcnt vmcnt(4)" ::: "memory");
        else     asm volatile("s_waitcnt vmcnt(0)" ::: "memory");
        FENCE(); __builtin_amdgcn_s_barrier(); FENCE();
        bf16x8 af[4], bfv[4];
#pragma unroll
        for (int f = 0; f < 4; ++f)
            af[f] = *(const bf16x8*)(As[cur] + (f * 16 + l15) * 128 + ((wm * 64 + lg * 16) ^ swz));
#pragma unroll
        for (int f = 0; f < 4; ++f)
            bfv[f] = *(const bf16x8*)(Bs[cur] + (f * 16 + l15) * 128 + ((wn * 64 + lg * 16) ^ swz));
        __builtin_amdgcn_s_setprio(1);
#pragma unroll
        for (int i = 0; i < 4; ++i)
#pragma unroll
            for (int j = 0; j < 4; ++j)
                acc[i][j] = mfma16(af[i], bfv[j], acc[i][j]);
        __builtin_amdgcn_s_setprio(0);
        FENCE(); __builtin_amdgcn_s_barrier(); FENCE();
    }

#pragma unroll
    for (int i = 0; i < 4; ++i) {
#pragma unroll
        for (int j = 0; j < 4; ++j) {
            const int n = n0 + wn * 64 + j * 16 + l15;
            const float bv = bias[n];
            const int mbase = m0 + wm * 64 + i * 16 + lg * 4;
#pragma unroll
            for (int r = 0; r < 4; ++r) {
                const int m = mbase + r;
                const float val = (acc[i][j][r] + bv) * scale;
                if (mode == 2) {
                    ((float*)outp)[(size_t)m * EMB + n] = val;
                } else {
                    const int b = m >> 12, t = m & (TSEQ - 1);
                    const int h = n >> 6, d = n & 63;
                    size_t addr;
                    if (mode == 0) addr = ((size_t)(b * NH + h) * TSEQ + t) * DH + d;
                    else           addr = ((size_t)(b * NH + h) * DH + d) * TSEQ + t;
                    ((__hip_bfloat16*)outp)[addr] = __float2bfloat16(val);
                }
            }
        }
    }
}

__global__ __launch_bounds__(256) void qkv_k(const __hip_bfloat16* __restrict__ xb,
                                             const __hip_bfloat16* __restrict__ wqT,
                                             const __hip_bfloat16* __restrict__ wkT,
                                             const __hip_bfloat16* __restrict__ wvT,
                                             const float* __restrict__ bq,
                                             const float* __restrict__ bk,
                                             const float* __restrict__ bv,
                                             __hip_bfloat16* __restrict__ qo,
                                             __hip_bfloat16* __restrict__ ko,
                                             __hip_bfloat16* __restrict__ vo) {
    const __hip_bfloat16* Wt; const float* bias; void* o; int mode; float scale;
    const float cq = 0.125f * 1.44269504089f;  // softmax scale * log2(e), folded into Q
    switch (blockIdx.z) {
        case 0:  Wt = wqT; bias = bq; o = qo; mode = 0; scale = cq;  break;
        case 1:  Wt = wkT; bias = bk; o = ko; mode = 0; scale = 1.f; break;
        default: Wt = wvT; bias = bv; o = vo; mode = 1; scale = 1.f; break;
    }
    gemm_body(xb, Wt, bias, o, mode, scale);
}

__global__ __launch_bounds__(256) void oproj_k(const __hip_bfloat16* __restrict__ abf,
                                               const __hip_bfloat16* __restrict__ woT,
                                               const float* __restrict__ bo,
                                               float* __restrict__ out) {
    gemm_body(abf, woT, bo, out, 2, 1.f);
}

// ---------- flash attention ----------
// Q (pre-scaled by 0.125*log2e), K: (B,H,T,D) bf16. V: (B,H,D,T) bf16.
// Block = 64 q-rows (4 waves x 16 rows), folded tile pair (i, 63-i): every
// wave does exactly 65 s-blocks. Grid 768 = 3 blocks/CU, zero tail.
// K/V tiles (64x64 bf16 each) cooperatively staged to LDS, double-buffered,
// counted vmcnt + raw barriers (prefetch survives the barrier). XOR-swizzled
// LDS (linear gload_lds dest + inverse-swizzled global source + swizzled read).
__global__ __launch_bounds__(256) void attn_k(const __hip_bfloat16* __restrict__ qb,
                                              const __hip_bfloat16* __restrict__ kb,
                                              const __hip_bfloat16* __restrict__ vt,
                                              __hip_bfloat16* __restrict__ ab) {
    __shared__ alignas(16) char Ks[2][8192];
    __shared__ alignas(16) char Vs[2][8192];
    __shared__ alignas(16) char pbuf[4][2048];  // per-wave P bounce, swizzled
    const int lane = threadIdx.x & 63, l15 = lane & 15, lg = lane >> 4;
    const int wave = threadIdx.x >> 6;
    const int bid = blockIdx.x;
    const int xcd = bid & 7, slot = bid >> 3;
    const int pair = slot & 31, hgrp = slot >> 5;
    const int bh = xcd + hgrp * 8;           // head-clustered XCD mapping
    const __hip_bfloat16* Qh = qb + (size_t)bh * TSEQ * DH;
    const __hip_bfloat16* Kh = kb + (size_t)bh * TSEQ * DH;
    const __hip_bfloat16* Vh = vt + (size_t)bh * DH * TSEQ;
    char* Pb = pbuf[wave];
    const int swz = (l15 & 7) << 4;
    const int b = bh / NH, h = bh % NH;

    // staging geometry: chunk c: linear p = c*4096 + wave*1024 + lane*16
    int r_[2], wp_[2];
#pragma unroll
    for (int c = 0; c < 2; ++c) {
        int p = c * 4096 + wave * 1024 + lane * 16;
        int r = p >> 7, w = p & 127;
        r_[c] = r;
        wp_[c] = (w ^ ((r & 7) << 4)) >> 1;  // element offset within row
    }

    auto stageKV = [&](int buf, int s0) {
#pragma unroll
        for (int c = 0; c < 2; ++c)
            gload16(Kh + (size_t)(s0 + r_[c]) * DH + wp_[c], Ks[buf] + c * 4096 + wave * 1024);
#pragma unroll
        for (int c = 0; c < 2; ++c)
            gload16(Vh + (size_t)r_[c] * TSEQ + s0 + wp_[c], Vs[buf] + c * 4096 + wave * 1024);
    };
    auto rdK = [&](int buf, int st, int ks) {
        return *(const bf16x8*)(Ks[buf] + (st * 16 + l15) * 128 + ((ks * 64 + lg * 16) ^ swz));
    };
    auto rdV = [&](int buf, int dt, int ks) {
        return *(const bf16x8*)(Vs[buf] + (dt * 16 + l15) * 128 + ((ks * 64 + lg * 16) ^ swz));
    };

    for (int tt = 0; tt < 2; ++tt) {
        const int tile = tt ? (63 - pair) : pair;
        const int q0 = tile * 64 + wave * 16;
        const int qcol = q0 + l15;

        bf16x8 qf[2];
#pragma unroll
        for (int ks = 0; ks < 2; ++ks)
            qf[ks] = *(const bf16x8*)(Qh + (size_t)(q0 + l15) * DH + ks * 32 + lg * 8);

        f32x4 o[4];
#pragma unroll
        for (int dt = 0; dt < 4; ++dt) o[dt] = (f32x4){0.f, 0.f, 0.f, 0.f};
        float m = -1e30f, lsum = 0.f;

        const int nsb = tile + 1;
        stageKV(0, 0);
        for (int sb = 0; sb < nsb; ++sb) {
            const int cur = sb & 1;
            const bool pre = (sb + 1 < nsb);
            if (pre) stageKV(cur ^ 1, (sb + 1) << 6);
            if (pre) asm volatile("s_waitcnt vmcnt(4)" ::: "memory");
            else     asm volatile("s_waitcnt vmcnt(0)" ::: "memory");
            FENCE(); __builtin_amdgcn_s_barrier(); FENCE();

            const int s0 = sb << 6;
            // S^T tiles: D[row = s-in-tile, col = q = l15], log2-domain
            f32x4 sa[4];
            __builtin_amdgcn_s_setprio(1);
#pragma unroll
            for (int st = 0; st < 4; ++st) {
                f32x4 z = (f32x4){0.f, 0.f, 0.f, 0.f};
                z = mfma16(rdK(cur, st, 0), qf[0], z);
                z = mfma16(rdK(cur, st, 1), qf[1], z);
                sa[st] = z;
            }
            __builtin_amdgcn_s_setprio(0);
            if (s0 + 63 > qcol) {
#pragma unroll
                for (int st = 0; st < 4; ++st)
#pragma unroll
                    for (int r = 0; r < 4; ++r)
                        if (s0 + st * 16 + lg * 4 + r > qcol) sa[st][r] = -INFINITY;
            }
            float mx = -1e30f;
#pragma unroll
            for (int st = 0; st < 4; ++st)
#pragma unroll
                for (int r = 0; r < 4; ++r) mx = fmaxf(mx, sa[st][r]);
            mx = fmaxf(mx, __shfl_xor(mx, 16));
            mx = fmaxf(mx, __shfl_xor(mx, 32));

            // defer-max (T13): skip rescale when column max grew <= 8
            float mnew = m;
            if (!__all(mx <= m + 8.0f)) {
                mnew = fmaxf(m, mx);
                const float rescale = exp2f(m - mnew);
                m = mnew;
                float fr[4];
#pragma unroll
                for (int r = 0; r < 4; ++r) fr[r] = __shfl(rescale, lg * 4 + r);
#pragma unroll
                for (int dt = 0; dt < 4; ++dt) {
                    f32x4 ov = o[dt];
#pragma unroll
                    for (int r = 0; r < 4; ++r) ov[r] *= fr[r];
                    o[dt] = ov;
                }
                lsum *= rescale;
            }

            float sum = 0.f;
#pragma unroll
            for (int st = 0; st < 4; ++st) {
                union { unsigned short u[4]; uint2 v; } pk;
#pragma unroll
                for (int r = 0; r < 4; ++r) {
                    const float p = exp2f(sa[st][r] - mnew);
                    sum += p;
                    __hip_bfloat16 hb = __float2bfloat16(p);
                    pk.u[r] = *(unsigned short*)&hb;
                }
                *(uint2*)(Pb + l15 * 128 + ((st * 32 + lg * 8) ^ swz)) = pk.v;
            }
            sum += __shfl_xor(sum, 16);
            sum += __shfl_xor(sum, 32);
            lsum += sum;

            asm volatile("s_waitcnt lgkmcnt(0)" ::: "memory");  // P writes visible
            __builtin_amdgcn_s_setprio(1);
#pragma unroll
            for (int ks = 0; ks < 2; ++ks) {
                bf16x8 pf = *(const bf16x8*)(Pb + l15 * 128 + ((ks * 64 + lg * 16) ^ swz));
#pragma unroll
                for (int dt = 0; dt < 4; ++dt)
                    o[dt] = mfma16(pf, rdV(cur, dt, ks), o[dt]);
            }
            __builtin_amdgcn_s_setprio(0);
            asm volatile("s_waitcnt lgkmcnt(0)" ::: "memory");  // P reads done

            FENCE(); __builtin_amdgcn_s_barrier(); FENCE();
        }

        const float linv = 1.0f / lsum;
        float lr[4];
#pragma unroll
        for (int r = 0; r < 4; ++r) lr[r] = __shfl(linv, lg * 4 + r);
#pragma unroll
        for (int r = 0; r < 4; ++r) {
            const int qrow = q0 + lg * 4 + r;
            const size_t rowbase = ((size_t)b * TSEQ + qrow) * EMB + h * DH;
#pragma unroll
            for (int dt = 0; dt < 4; ++dt)
                ab[rowbase + dt * 16 + l15] = __float2bfloat16(o[dt][r] * lr[r]);
        }
    }
}

extern "C" void kernel_launch(void* const* d_in, const int* in_sizes, int n_in,
                              void* d_out, int out_size, void* d_ws, size_t ws_size,
                              hipStream_t stream) {
    (void)in_sizes; (void)n_in; (void)out_size; (void)ws_size;
    const float* x  = (const float*)d_in[0];
    const float* wq = (const float*)d_in[1];
    const float* bq = (const float*)d_in[2];
    const float* wk = (const float*)d_in[3];
    const float* bk = (const float*)d_in[4];
    const float* wv = (const float*)d_in[5];
    const float* bv = (const float*)d_in[6];
    const float* wo = (const float*)d_in[7];
    const float* bo = (const float*)d_in[8];
    float* out = (float*)d_out;

    char* ws = (char*)d_ws;
    size_t off = 0;
    auto alloc = [&](size_t bytes) {
        char* p = ws + off;
        off += (bytes + 255) & ~(size_t)255;
        return p;
    };
    __hip_bfloat16* xb  = (__hip_bfloat16*)alloc((size_t)BT * EMB * 2);
    __hip_bfloat16* qbf = (__hip_bfloat16*)alloc((size_t)BT * EMB * 2);
    __hip_bfloat16* kbf = (__hip_bfloat16*)alloc((size_t)BT * EMB * 2);
    __hip_bfloat16* vtb = (__hip_bfloat16*)alloc((size_t)BT * EMB * 2);
    __hip_bfloat16* abf = (__hip_bfloat16*)alloc((size_t)BT * EMB * 2);
    __hip_bfloat16* wqT = (__hip_bfloat16*)alloc((size_t)EMB * EMB * 2);
    __hip_bfloat16* wkT = (__hip_bfloat16*)alloc((size_t)EMB * EMB * 2);
    __hip_bfloat16* wvT = (__hip_bfloat16*)alloc((size_t)EMB * EMB * 2);
    __hip_bfloat16* woT = (__hip_bfloat16*)alloc((size_t)EMB * EMB * 2);

    conv_x_k<<<BT * EMB / 1024, 256, 0, stream>>>(x, xb);
    conv_w_k<<<dim3(24, 24, 4), 256, 0, stream>>>(wq, wk, wv, wo, wqT, wkT, wvT, woT);
    qkv_k<<<dim3(64, 6, 3), 256, 0, stream>>>(xb, wqT, wkT, wvT, bq, bk, bv, qbf, kbf, vtb);
    attn_k<<<768, 256, 0, stream>>>(qbf, kbf, vtb, abf);
    oproj_k<<<dim3(64, 6), 256, 0, stream>>>(abf, woT, bo, out);
}

// Round 5
// 207.806 us; speedup vs baseline: 3.2575x; 1.0495x over previous
//
#include <hip/hip_runtime.h>
#include <hip/hip_bf16.h>

#define TSEQ 4096
#define EMB 768
#define NH 12
#define DH 64
#define BT 8192  // B*T

typedef __attribute__((ext_vector_type(8))) short bf16x8;
typedef __attribute__((ext_vector_type(4))) float f32x4;

#define FENCE() asm volatile("" ::: "memory")

__device__ __forceinline__ f32x4 mfma16(bf16x8 a, bf16x8 b, f32x4 c) {
    return __builtin_amdgcn_mfma_f32_16x16x32_bf16(a, b, c, 0, 0, 0);
}

__device__ __forceinline__ void gload16(const void* g, void* l) {
    __builtin_amdgcn_global_load_lds((const __attribute__((address_space(1))) void*)g,
                                     (__attribute__((address_space(3))) void*)l, 16, 0, 0);
}

// ---------- conversion kernels ----------
__global__ __launch_bounds__(256) void conv_x_k(const float* __restrict__ x,
                                                __hip_bfloat16* __restrict__ xb) {
    int i = (blockIdx.x * 256 + threadIdx.x) * 4;
    float4 v = *(const float4*)(x + i);
    union { unsigned short u[4]; uint2 p; } o;
    __hip_bfloat16 t0 = __float2bfloat16(v.x); o.u[0] = *(unsigned short*)&t0;
    __hip_bfloat16 t1 = __float2bfloat16(v.y); o.u[1] = *(unsigned short*)&t1;
    __hip_bfloat16 t2 = __float2bfloat16(v.z); o.u[2] = *(unsigned short*)&t2;
    __hip_bfloat16 t3 = __float2bfloat16(v.w); o.u[3] = *(unsigned short*)&t3;
    *(uint2*)(xb + i) = o.p;
}

// transpose 768x768 fp32 (k,n) -> bf16 (n,k); z selects which weight
__global__ __launch_bounds__(256) void conv_w_k(const float* w0, const float* w1,
                                                const float* w2, const float* w3,
                                                __hip_bfloat16* o0, __hip_bfloat16* o1,
                                                __hip_bfloat16* o2, __hip_bfloat16* o3) {
    const float* w; __hip_bfloat16* o;
    switch (blockIdx.z) {
        case 0: w = w0; o = o0; break;
        case 1: w = w1; o = o1; break;
        case 2: w = w2; o = o2; break;
        default: w = w3; o = o3; break;
    }
    __shared__ float tile[32][33];
    int tx = threadIdx.x & 31, ty = threadIdx.x >> 5;  // 32 x 8
    int kb = blockIdx.y * 32, nb = blockIdx.x * 32;
    for (int i = 0; i < 32; i += 8)
        tile[ty + i][tx] = w[(size_t)(kb + ty + i) * EMB + nb + tx];
    __syncthreads();
    for (int i = 0; i < 32; i += 8)
        o[(size_t)(nb + ty + i) * EMB + kb + tx] = __float2bfloat16(tile[tx][ty + i]);
}

// ---------- GEMM body: C(M,N) = scale * (A(M,K) * Wt(N,K)^T + bias) ----------
// LDS tile: 64 "rows" x 128B; XOR-swizzled (byte ^= (lrow&7)<<4), staged with
// inverse-swizzled global source (gload_lds writes linearly).
// mode 0: write bf16 (B,H,T,D); mode 1: bf16 (B,H,D,T); mode 2: fp32 (M,N).
__device__ __forceinline__ void gemm_body(const __hip_bfloat16* __restrict__ A,
                                          const __hip_bfloat16* __restrict__ Wt,
                                          const float* __restrict__ bias,
                                          void* __restrict__ outp, int mode, float scale) {
    __shared__ alignas(16) char As[2][8192];
    __shared__ alignas(16) char Bs[2][8192];
    const int m0 = blockIdx.x * 128, n0 = blockIdx.y * 128;
    const int tid = threadIdx.x;
    const int lane = tid & 63, l15 = lane & 15, lg = lane >> 4;
    const int wave = tid >> 6, wm = wave >> 1, wn = wave & 1;
    const int swz = (l15 & 7) << 4;

    int mrow_[2]; int kelem_[2];
#pragma unroll
    for (int c = 0; c < 2; ++c) {
        int p = c * 4096 + tid * 16;
        int lrow = p >> 7, w = p & 127;
        int wp = w ^ ((lrow & 7) << 4);
        mrow_[c] = lrow + ((wp >> 6) & 1) * 64;
        kelem_[c] = (wp & 63) >> 1;
    }

    f32x4 acc[4][4];
    for (int i = 0; i < 4; ++i)
        for (int j = 0; j < 4; ++j) acc[i][j] = (f32x4){0.f, 0.f, 0.f, 0.f};

    auto stage = [&](int buf, int k0) {
#pragma unroll
        for (int c = 0; c < 2; ++c)
            gload16(A + (size_t)(m0 + mrow_[c]) * EMB + k0 + kelem_[c],
                    As[buf] + c * 4096 + wave * 1024);
#pragma unroll
        for (int c = 0; c < 2; ++c)
            gload16(Wt + (size_t)(n0 + mrow_[c]) * EMB + k0 + kelem_[c],
                    Bs[buf] + c * 4096 + wave * 1024);
    };

    stage(0, 0);
    const int NK = EMB / 32;
    for (int ks = 0; ks < NK; ++ks) {
        const int cur = ks & 1;
        const bool pre = (ks + 1 < NK);
        if (pre) stage(cur ^ 1, (ks + 1) * 32);
        if (pre) asm volatile("s_waitcnt vmcnt(4)" ::: "memory");
        else     asm volatile("s_waitcnt vmcnt(0)" ::: "memory");
        FENCE(); __builtin_amdgcn_s_barrier(); FENCE();
        bf16x8 af[4], bfv[4];
#pragma unroll
        for (int f = 0; f < 4; ++f)
            af[f] = *(const bf16x8*)(As[cur] + (f * 16 + l15) * 128 + ((wm * 64 + lg * 16) ^ swz));
#pragma unroll
        for (int f = 0; f < 4; ++f)
            bfv[f] = *(const bf16x8*)(Bs[cur] + (f * 16 + l15) * 128 + ((wn * 64 + lg * 16) ^ swz));
        __builtin_amdgcn_s_setprio(1);
#pragma unroll
        for (int i = 0; i < 4; ++i)
#pragma unroll
            for (int j = 0; j < 4; ++j)
                acc[i][j] = mfma16(af[i], bfv[j], acc[i][j]);
        __builtin_amdgcn_s_setprio(0);
        FENCE(); __builtin_amdgcn_s_barrier(); FENCE();
    }

#pragma unroll
    for (int i = 0; i < 4; ++i) {
#pragma unroll
        for (int j = 0; j < 4; ++j) {
            const int n = n0 + wn * 64 + j * 16 + l15;
            const float bv = bias[n];
            const int mbase = m0 + wm * 64 + i * 16 + lg * 4;
#pragma unroll
            for (int r = 0; r < 4; ++r) {
                const int m = mbase + r;
                const float val = (acc[i][j][r] + bv) * scale;
                if (mode == 2) {
                    ((float*)outp)[(size_t)m * EMB + n] = val;
                } else {
                    const int b = m >> 12, t = m & (TSEQ - 1);
                    const int h = n >> 6, d = n & 63;
                    size_t addr;
                    if (mode == 0) addr = ((size_t)(b * NH + h) * TSEQ + t) * DH + d;
                    else           addr = ((size_t)(b * NH + h) * DH + d) * TSEQ + t;
                    ((__hip_bfloat16*)outp)[addr] = __float2bfloat16(val);
                }
            }
        }
    }
}

__global__ __launch_bounds__(256) void qkv_k(const __hip_bfloat16* __restrict__ xb,
                                             const __hip_bfloat16* __restrict__ wqT,
                                             const __hip_bfloat16* __restrict__ wkT,
                                             const __hip_bfloat16* __restrict__ wvT,
                                             const float* __restrict__ bq,
                                             const float* __restrict__ bk,
                                             const float* __restrict__ bv,
                                             __hip_bfloat16* __restrict__ qo,
                                             __hip_bfloat16* __restrict__ ko,
                                             __hip_bfloat16* __restrict__ vo) {
    const __hip_bfloat16* Wt; const float* bias; void* o; int mode; float scale;
    const float cq = 0.125f * 1.44269504089f;  // softmax scale * log2(e), folded into Q
    switch (blockIdx.z) {
        case 0:  Wt = wqT; bias = bq; o = qo; mode = 0; scale = cq;  break;
        case 1:  Wt = wkT; bias = bk; o = ko; mode = 0; scale = 1.f; break;
        default: Wt = wvT; bias = bv; o = vo; mode = 1; scale = 1.f; break;
    }
    gemm_body(xb, Wt, bias, o, mode, scale);
}

__global__ __launch_bounds__(256) void oproj_k(const __hip_bfloat16* __restrict__ abf,
                                               const __hip_bfloat16* __restrict__ woT,
                                               const float* __restrict__ bo,
                                               float* __restrict__ out) {
    gemm_body(abf, woT, bo, out, 2, 1.f);
}

// ---------- flash attention ----------
// Q (pre-scaled by 0.125*log2e), K: (B,H,T,D) bf16. V: (B,H,D,T) bf16.
// Block = 64 q-rows (4 waves x 16 rows), folded tile pair (i, 63-i): every
// wave does exactly 65 s-blocks. Grid 768 = 3 blocks/CU, zero tail.
// K/V staged to LDS double-buffered (counted vmcnt + raw barriers, XOR swizzle).
// Softmax denominator accumulated on the MFMA pipe via all-ones B-fragment:
// lacc rows align with O rows -> no shfl for sum or final normalization.
__global__ __launch_bounds__(256) void attn_k(const __hip_bfloat16* __restrict__ qb,
                                              const __hip_bfloat16* __restrict__ kb,
                                              const __hip_bfloat16* __restrict__ vt,
                                              __hip_bfloat16* __restrict__ ab) {
    __shared__ alignas(16) char Ks[2][8192];
    __shared__ alignas(16) char Vs[2][8192];
    __shared__ alignas(16) char pbuf[4][2048];  // per-wave P bounce, swizzled
    const int lane = threadIdx.x & 63, l15 = lane & 15, lg = lane >> 4;
    const int wave = threadIdx.x >> 6;
    const int bid = blockIdx.x;
    const int xcd = bid & 7, slot = bid >> 3;
    const int pair = slot & 31, hgrp = slot >> 5;
    const int bh = xcd + hgrp * 8;           // head-clustered XCD mapping
    const __hip_bfloat16* Qh = qb + (size_t)bh * TSEQ * DH;
    const __hip_bfloat16* Kh = kb + (size_t)bh * TSEQ * DH;
    const __hip_bfloat16* Vh = vt + (size_t)bh * DH * TSEQ;
    char* Pb = pbuf[wave];
    const int swz = (l15 & 7) << 4;
    const int b = bh / NH, h = bh % NH;

    bf16x8 ones8;
#pragma unroll
    for (int j = 0; j < 8; ++j) ones8[j] = (short)0x3F80;  // bf16 1.0

    // staging geometry: chunk c: linear p = c*4096 + wave*1024 + lane*16
    int r_[2], wp_[2];
#pragma unroll
    for (int c = 0; c < 2; ++c) {
        int p = c * 4096 + wave * 1024 + lane * 16;
        int r = p >> 7, w = p & 127;
        r_[c] = r;
        wp_[c] = (w ^ ((r & 7) << 4)) >> 1;  // element offset within row
    }

    auto stageKV = [&](int buf, int s0) {
#pragma unroll
        for (int c = 0; c < 2; ++c)
            gload16(Kh + (size_t)(s0 + r_[c]) * DH + wp_[c], Ks[buf] + c * 4096 + wave * 1024);
#pragma unroll
        for (int c = 0; c < 2; ++c)
            gload16(Vh + (size_t)r_[c] * TSEQ + s0 + wp_[c], Vs[buf] + c * 4096 + wave * 1024);
    };
    auto rdK = [&](int buf, int st, int ks) {
        return *(const bf16x8*)(Ks[buf] + (st * 16 + l15) * 128 + ((ks * 64 + lg * 16) ^ swz));
    };
    auto rdV = [&](int buf, int dt, int ks) {
        return *(const bf16x8*)(Vs[buf] + (dt * 16 + l15) * 128 + ((ks * 64 + lg * 16) ^ swz));
    };

    for (int tt = 0; tt < 2; ++tt) {
        const int tile = tt ? (63 - pair) : pair;
        const int q0 = tile * 64 + wave * 16;
        const int qcol = q0 + l15;

        bf16x8 qf[2];
#pragma unroll
        for (int ks = 0; ks < 2; ++ks)
            qf[ks] = *(const bf16x8*)(Qh + (size_t)(q0 + l15) * DH + ks * 32 + lg * 8);

        f32x4 o[4];
#pragma unroll
        for (int dt = 0; dt < 4; ++dt) o[dt] = (f32x4){0.f, 0.f, 0.f, 0.f};
        f32x4 lacc = (f32x4){0.f, 0.f, 0.f, 0.f};  // softmax denom, rows = o rows
        float m = -1e30f;

        const int nsb = tile + 1;
        stageKV(0, 0);
        for (int sb = 0; sb < nsb; ++sb) {
            const int cur = sb & 1;
            const bool pre = (sb + 1 < nsb);
            if (pre) stageKV(cur ^ 1, (sb + 1) << 6);
            if (pre) asm volatile("s_waitcnt vmcnt(4)" ::: "memory");
            else     asm volatile("s_waitcnt vmcnt(0)" ::: "memory");
            FENCE(); __builtin_amdgcn_s_barrier(); FENCE();

            const int s0 = sb << 6;
            // S^T tiles: D[row = s-in-tile, col = q = l15], log2-domain
            f32x4 sa[4];
            __builtin_amdgcn_s_setprio(1);
#pragma unroll
            for (int st = 0; st < 4; ++st) {
                f32x4 z = (f32x4){0.f, 0.f, 0.f, 0.f};
                z = mfma16(rdK(cur, st, 0), qf[0], z);
                z = mfma16(rdK(cur, st, 1), qf[1], z);
                sa[st] = z;
            }
            __builtin_amdgcn_s_setprio(0);
            if (s0 + 63 > qcol) {
#pragma unroll
                for (int st = 0; st < 4; ++st)
#pragma unroll
                    for (int r = 0; r < 4; ++r)
                        if (s0 + st * 16 + lg * 4 + r > qcol) sa[st][r] = -INFINITY;
            }
            // grouped triples -> v_max3_f32 (8 ops)
            float mx = fmaxf(fmaxf(sa[0][0], sa[0][1]), sa[0][2]);
            mx = fmaxf(fmaxf(mx, sa[0][3]), sa[1][0]);
            mx = fmaxf(fmaxf(mx, sa[1][1]), sa[1][2]);
            mx = fmaxf(fmaxf(mx, sa[1][3]), sa[2][0]);
            mx = fmaxf(fmaxf(mx, sa[2][1]), sa[2][2]);
            mx = fmaxf(fmaxf(mx, sa[2][3]), sa[3][0]);
            mx = fmaxf(fmaxf(mx, sa[3][1]), sa[3][2]);
            mx = fmaxf(mx, sa[3][3]);
            mx = fmaxf(mx, __shfl_xor(mx, 16));
            mx = fmaxf(mx, __shfl_xor(mx, 32));

            // defer-max (T13): skip rescale when column max grew <= 8
            float mnew = m;
            if (!__all(mx <= m + 8.0f)) {
                mnew = fmaxf(m, mx);
                const float rescale = exp2f(m - mnew);
                m = mnew;
                float fr[4];
#pragma unroll
                for (int r = 0; r < 4; ++r) fr[r] = __shfl(rescale, lg * 4 + r);
#pragma unroll
                for (int dt = 0; dt < 4; ++dt) {
                    f32x4 ov = o[dt];
#pragma unroll
                    for (int r = 0; r < 4; ++r) ov[r] *= fr[r];
                    o[dt] = ov;
                }
#pragma unroll
                for (int r = 0; r < 4; ++r) lacc[r] *= fr[r];
            }

#pragma unroll
            for (int st = 0; st < 4; ++st) {
                union { unsigned short u[4]; uint2 v; } pk;
#pragma unroll
                for (int r = 0; r < 4; ++r) {
                    const float p = exp2f(sa[st][r] - mnew);
                    __hip_bfloat16 hb = __float2bfloat16(p);
                    pk.u[r] = *(unsigned short*)&hb;
                }
                *(uint2*)(Pb + l15 * 128 + ((st * 32 + lg * 8) ^ swz)) = pk.v;
            }

            asm volatile("s_waitcnt lgkmcnt(0)" ::: "memory");  // P writes visible
            __builtin_amdgcn_s_setprio(1);
            bf16x8 pf0 = *(const bf16x8*)(Pb + l15 * 128 + ((0 * 64 + lg * 16) ^ swz));
            bf16x8 pf1 = *(const bf16x8*)(Pb + l15 * 128 + ((1 * 64 + lg * 16) ^ swz));
            lacc = mfma16(pf0, ones8, lacc);  // denom on the matrix pipe
            lacc = mfma16(pf1, ones8, lacc);
#pragma unroll
            for (int dt = 0; dt < 4; ++dt)
                o[dt] = mfma16(pf0, rdV(cur, dt, 0), o[dt]);
#pragma unroll
            for (int dt = 0; dt < 4; ++dt)
                o[dt] = mfma16(pf1, rdV(cur, dt, 1), o[dt]);
            __builtin_amdgcn_s_setprio(0);
            asm volatile("s_waitcnt lgkmcnt(0)" ::: "memory");  // P reads done

            FENCE(); __builtin_amdgcn_s_barrier(); FENCE();
        }

        float inv[4];
#pragma unroll
        for (int r = 0; r < 4; ++r) inv[r] = 1.0f / lacc[r];
#pragma unroll
        for (int r = 0; r < 4; ++r) {
            const int qrow = q0 + lg * 4 + r;
            const size_t rowbase = ((size_t)b * TSEQ + qrow) * EMB + h * DH;
#pragma unroll
            for (int dt = 0; dt < 4; ++dt)
                ab[rowbase + dt * 16 + l15] = __float2bfloat16(o[dt][r] * inv[r]);
        }
    }
}

extern "C" void kernel_launch(void* const* d_in, const int* in_sizes, int n_in,
                              void* d_out, int out_size, void* d_ws, size_t ws_size,
                              hipStream_t stream) {
    (void)in_sizes; (void)n_in; (void)out_size; (void)ws_size;
    const float* x  = (const float*)d_in[0];
    const float* wq = (const float*)d_in[1];
    const float* bq = (const float*)d_in[2];
    const float* wk = (const float*)d_in[3];
    const float* bk = (const float*)d_in[4];
    const float* wv = (const float*)d_in[5];
    const float* bv = (const float*)d_in[6];
    const float* wo = (const float*)d_in[7];
    const float* bo = (const float*)d_in[8];
    float* out = (float*)d_out;

    char* ws = (char*)d_ws;
    size_t off = 0;
    auto alloc = [&](size_t bytes) {
        char* p = ws + off;
        off += (bytes + 255) & ~(size_t)255;
        return p;
    };
    __hip_bfloat16* xb  = (__hip_bfloat16*)alloc((size_t)BT * EMB * 2);
    __hip_bfloat16* qbf = (__hip_bfloat16*)alloc((size_t)BT * EMB * 2);
    __hip_bfloat16* kbf = (__hip_bfloat16*)alloc((size_t)BT * EMB * 2);
    __hip_bfloat16* vtb = (__hip_bfloat16*)alloc((size_t)BT * EMB * 2);
    __hip_bfloat16* abf = (__hip_bfloat16*)alloc((size_t)BT * EMB * 2);
    __hip_bfloat16* wqT = (__hip_bfloat16*)alloc((size_t)EMB * EMB * 2);
    __hip_bfloat16* wkT = (__hip_bfloat16*)alloc((size_t)EMB * EMB * 2);
    __hip_bfloat16* wvT = (__hip_bfloat16*)alloc((size_t)EMB * EMB * 2);
    __hip_bfloat16* woT = (__hip_bfloat16*)alloc((size_t)EMB * EMB * 2);

    conv_x_k<<<BT * EMB / 1024, 256, 0, stream>>>(x, xb);
    conv_w_k<<<dim3(24, 24, 4), 256, 0, stream>>>(wq, wk, wv, wo, wqT, wkT, wvT, woT);
    qkv_k<<<dim3(64, 6, 3), 256, 0, stream>>>(xb, wqT, wkT, wvT, bq, bk, bv, qbf, kbf, vtb);
    attn_k<<<768, 256, 0, stream>>>(qbf, kbf, vtb, abf);
    oproj_k<<<dim3(64, 6), 256, 0, stream>>>(abf, woT, bo, out);
}

// Round 6
// 207.802 us; speedup vs baseline: 3.2576x; 1.0000x over previous
//
#include <hip/hip_runtime.h>
#include <hip/hip_bf16.h>

#define TSEQ 4096
#define EMB 768
#define NH 12
#define DH 64
#define BT 8192  // B*T

typedef __attribute__((ext_vector_type(8))) short bf16x8;
typedef __attribute__((ext_vector_type(4))) float f32x4;

#define FENCE() asm volatile("" ::: "memory")

__device__ __forceinline__ f32x4 mfma16(bf16x8 a, bf16x8 b, f32x4 c) {
    return __builtin_amdgcn_mfma_f32_16x16x32_bf16(a, b, c, 0, 0, 0);
}

__device__ __forceinline__ void gload16(const void* g, void* l) {
    __builtin_amdgcn_global_load_lds((const __attribute__((address_space(1))) void*)g,
                                     (__attribute__((address_space(3))) void*)l, 16, 0, 0);
}

// ---------- conversion kernels ----------
__global__ __launch_bounds__(256) void conv_x_k(const float* __restrict__ x,
                                                __hip_bfloat16* __restrict__ xb) {
    int i = (blockIdx.x * 256 + threadIdx.x) * 4;
    float4 v = *(const float4*)(x + i);
    union { unsigned short u[4]; uint2 p; } o;
    __hip_bfloat16 t0 = __float2bfloat16(v.x); o.u[0] = *(unsigned short*)&t0;
    __hip_bfloat16 t1 = __float2bfloat16(v.y); o.u[1] = *(unsigned short*)&t1;
    __hip_bfloat16 t2 = __float2bfloat16(v.z); o.u[2] = *(unsigned short*)&t2;
    __hip_bfloat16 t3 = __float2bfloat16(v.w); o.u[3] = *(unsigned short*)&t3;
    *(uint2*)(xb + i) = o.p;
}

// transpose 768x768 fp32 (k,n) -> bf16 (n,k); z selects which weight
__global__ __launch_bounds__(256) void conv_w_k(const float* w0, const float* w1,
                                                const float* w2, const float* w3,
                                                __hip_bfloat16* o0, __hip_bfloat16* o1,
                                                __hip_bfloat16* o2, __hip_bfloat16* o3) {
    const float* w; __hip_bfloat16* o;
    switch (blockIdx.z) {
        case 0: w = w0; o = o0; break;
        case 1: w = w1; o = o1; break;
        case 2: w = w2; o = o2; break;
        default: w = w3; o = o3; break;
    }
    __shared__ float tile[32][33];
    int tx = threadIdx.x & 31, ty = threadIdx.x >> 5;  // 32 x 8
    int kb = blockIdx.y * 32, nb = blockIdx.x * 32;
    for (int i = 0; i < 32; i += 8)
        tile[ty + i][tx] = w[(size_t)(kb + ty + i) * EMB + nb + tx];
    __syncthreads();
    for (int i = 0; i < 32; i += 8)
        o[(size_t)(nb + ty + i) * EMB + kb + tx] = __float2bfloat16(tile[tx][ty + i]);
}

// ---------- GEMM body: C(M,N) = scale * (A(M,K) * Wt(N,K)^T + bias) ----------
// LDS tile: 64 "rows" x 128B; XOR-swizzled (byte ^= (lrow&7)<<4), staged with
// inverse-swizzled global source (gload_lds writes linearly).
// mode 0: write bf16 (B,H,T,D); mode 1: bf16 (B,H,D,T); mode 2: fp32 (M,N).
__device__ __forceinline__ void gemm_body(const __hip_bfloat16* __restrict__ A,
                                          const __hip_bfloat16* __restrict__ Wt,
                                          const float* __restrict__ bias,
                                          void* __restrict__ outp, int mode, float scale) {
    __shared__ alignas(16) char As[2][8192];
    __shared__ alignas(16) char Bs[2][8192];
    const int m0 = blockIdx.x * 128, n0 = blockIdx.y * 128;
    const int tid = threadIdx.x;
    const int lane = tid & 63, l15 = lane & 15, lg = lane >> 4;
    const int wave = tid >> 6, wm = wave >> 1, wn = wave & 1;
    const int swz = (l15 & 7) << 4;

    int mrow_[2]; int kelem_[2];
#pragma unroll
    for (int c = 0; c < 2; ++c) {
        int p = c * 4096 + tid * 16;
        int lrow = p >> 7, w = p & 127;
        int wp = w ^ ((lrow & 7) << 4);
        mrow_[c] = lrow + ((wp >> 6) & 1) * 64;
        kelem_[c] = (wp & 63) >> 1;
    }

    f32x4 acc[4][4];
    for (int i = 0; i < 4; ++i)
        for (int j = 0; j < 4; ++j) acc[i][j] = (f32x4){0.f, 0.f, 0.f, 0.f};

    auto stage = [&](int buf, int k0) {
#pragma unroll
        for (int c = 0; c < 2; ++c)
            gload16(A + (size_t)(m0 + mrow_[c]) * EMB + k0 + kelem_[c],
                    As[buf] + c * 4096 + wave * 1024);
#pragma unroll
        for (int c = 0; c < 2; ++c)
            gload16(Wt + (size_t)(n0 + mrow_[c]) * EMB + k0 + kelem_[c],
                    Bs[buf] + c * 4096 + wave * 1024);
    };

    stage(0, 0);
    const int NK = EMB / 32;
    for (int ks = 0; ks < NK; ++ks) {
        const int cur = ks & 1;
        const bool pre = (ks + 1 < NK);
        if (pre) stage(cur ^ 1, (ks + 1) * 32);
        if (pre) asm volatile("s_waitcnt vmcnt(4)" ::: "memory");
        else     asm volatile("s_waitcnt vmcnt(0)" ::: "memory");
        FENCE(); __builtin_amdgcn_s_barrier(); FENCE();
        bf16x8 af[4], bfv[4];
#pragma unroll
        for (int f = 0; f < 4; ++f)
            af[f] = *(const bf16x8*)(As[cur] + (f * 16 + l15) * 128 + ((wm * 64 + lg * 16) ^ swz));
#pragma unroll
        for (int f = 0; f < 4; ++f)
            bfv[f] = *(const bf16x8*)(Bs[cur] + (f * 16 + l15) * 128 + ((wn * 64 + lg * 16) ^ swz));
        __builtin_amdgcn_s_setprio(1);
#pragma unroll
        for (int i = 0; i < 4; ++i)
#pragma unroll
            for (int j = 0; j < 4; ++j)
                acc[i][j] = mfma16(af[i], bfv[j], acc[i][j]);
        __builtin_amdgcn_s_setprio(0);
        FENCE(); __builtin_amdgcn_s_barrier(); FENCE();
    }

#pragma unroll
    for (int i = 0; i < 4; ++i) {
#pragma unroll
        for (int j = 0; j < 4; ++j) {
            const int n = n0 + wn * 64 + j * 16 + l15;
            const float bv = bias[n];
            const int mbase = m0 + wm * 64 + i * 16 + lg * 4;
#pragma unroll
            for (int r = 0; r < 4; ++r) {
                const int m = mbase + r;
                const float val = (acc[i][j][r] + bv) * scale;
                if (mode == 2) {
                    ((float*)outp)[(size_t)m * EMB + n] = val;
                } else {
                    const int b = m >> 12, t = m & (TSEQ - 1);
                    const int h = n >> 6, d = n & 63;
                    size_t addr;
                    if (mode == 0) addr = ((size_t)(b * NH + h) * TSEQ + t) * DH + d;
                    else           addr = ((size_t)(b * NH + h) * DH + d) * TSEQ + t;
                    ((__hip_bfloat16*)outp)[addr] = __float2bfloat16(val);
                }
            }
        }
    }
}

__global__ __launch_bounds__(256) void qkv_k(const __hip_bfloat16* __restrict__ xb,
                                             const __hip_bfloat16* __restrict__ wqT,
                                             const __hip_bfloat16* __restrict__ wkT,
                                             const __hip_bfloat16* __restrict__ wvT,
                                             const float* __restrict__ bq,
                                             const float* __restrict__ bk,
                                             const float* __restrict__ bv,
                                             __hip_bfloat16* __restrict__ qo,
                                             __hip_bfloat16* __restrict__ ko,
                                             __hip_bfloat16* __restrict__ vo) {
    const __hip_bfloat16* Wt; const float* bias; void* o; int mode; float scale;
    const float cq = 0.125f * 1.44269504089f;  // softmax scale * log2(e), folded into Q
    switch (blockIdx.z) {
        case 0:  Wt = wqT; bias = bq; o = qo; mode = 0; scale = cq;  break;
        case 1:  Wt = wkT; bias = bk; o = ko; mode = 0; scale = 1.f; break;
        default: Wt = wvT; bias = bv; o = vo; mode = 1; scale = 1.f; break;
    }
    gemm_body(xb, Wt, bias, o, mode, scale);
}

__global__ __launch_bounds__(256) void oproj_k(const __hip_bfloat16* __restrict__ abf,
                                               const __hip_bfloat16* __restrict__ woT,
                                               const float* __restrict__ bo,
                                               float* __restrict__ out) {
    gemm_body(abf, woT, bo, out, 2, 1.f);
}

// ---------- flash attention ----------
// Q (pre-scaled by 0.125*log2e), K: (B,H,T,D) bf16. V: (B,H,D,T) bf16.
// Block = 64 q-rows (4 waves x 16 rows), folded tile pair (i, 63-i): every
// wave does exactly 65 s-blocks. Grid 768 = 3 blocks/CU, zero tail.
// This round: all LDS addresses hoisted to registers (loop-invariant), buffer
// index made compile-time via explicit 2x-unrolled pair loop, global staging
// pointers bumped by constants. Goal: strip compiler-materialized VALU.
__global__ __launch_bounds__(256) void attn_k(const __hip_bfloat16* __restrict__ qb,
                                              const __hip_bfloat16* __restrict__ kb,
                                              const __hip_bfloat16* __restrict__ vt,
                                              __hip_bfloat16* __restrict__ ab) {
    __shared__ alignas(16) char Ks[2][8192];
    __shared__ alignas(16) char Vs[2][8192];
    __shared__ alignas(16) char pbuf[4][2048];  // per-wave P bounce, swizzled
    const int lane = threadIdx.x & 63, l15 = lane & 15, lg = lane >> 4;
    const int wave = threadIdx.x >> 6;
    const int bid = blockIdx.x;
    const int xcd = bid & 7, slot = bid >> 3;
    const int pair = slot & 31, hgrp = slot >> 5;
    const int bh = xcd + hgrp * 8;           // head-clustered XCD mapping
    const __hip_bfloat16* Qh = qb + (size_t)bh * TSEQ * DH;
    const __hip_bfloat16* Kh = kb + (size_t)bh * TSEQ * DH;
    const __hip_bfloat16* Vh = vt + (size_t)bh * DH * TSEQ;
    char* Pb = pbuf[wave];
    const int swz = (l15 & 7) << 4;
    const int b = bh / NH, h = bh % NH;

    bf16x8 ones8;
#pragma unroll
    for (int j = 0; j < 8; ++j) ones8[j] = (short)0x3F80;  // bf16 1.0

    // ---- hoisted loop-invariant addresses ----
    // K/V LDS read offsets (same formula for K and V tiles): [st*2+ks]
    unsigned ka[8];
#pragma unroll
    for (int st = 0; st < 4; ++st)
#pragma unroll
        for (int ks = 0; ks < 2; ++ks)
            ka[st * 2 + ks] = (unsigned)((st * 16 + l15) * 128 + ((ks * 64 + lg * 16) ^ swz));
    // P bounce pointers
    char* pw[4]; char* pr[2];
#pragma unroll
    for (int st = 0; st < 4; ++st) pw[st] = Pb + l15 * 128 + ((st * 32 + lg * 8) ^ swz);
#pragma unroll
    for (int ks = 0; ks < 2; ++ks) pr[ks] = Pb + l15 * 128 + ((ks * 64 + lg * 16) ^ swz);
    // causal mask threshold (tile-independent): mask when st*16 + r > dthr
    const int dthr = wave * 16 + l15 - lg * 4;

    // staging geometry: chunk c: linear p = c*4096 + wave*1024 + lane*16
    int r_[2], wp_[2];
#pragma unroll
    for (int c = 0; c < 2; ++c) {
        int p = c * 4096 + wave * 1024 + lane * 16;
        int r = p >> 7, w = p & 127;
        r_[c] = r;
        wp_[c] = (w ^ ((r & 7) << 4)) >> 1;  // element offset within row
    }

#define SBODY(BUF, PRE, MASKB) do {                                              \
    if (PRE) {                                                                   \
        gload16(kg0, Ks[(BUF) ^ 1] + wave * 1024);                               \
        gload16(kg1, Ks[(BUF) ^ 1] + 4096 + wave * 1024);                        \
        gload16(vg0, Vs[(BUF) ^ 1] + wave * 1024);                               \
        gload16(vg1, Vs[(BUF) ^ 1] + 4096 + wave * 1024);                        \
        kg0 += 8192; kg1 += 8192; vg0 += 128; vg1 += 128;                        \
        asm volatile("s_waitcnt vmcnt(4)" ::: "memory");                         \
    } else {                                                                     \
        asm volatile("s_waitcnt vmcnt(0)" ::: "memory");                         \
    }                                                                            \
    FENCE(); __builtin_amdgcn_s_barrier(); FENCE();                              \
    f32x4 sa[4];                                                                 \
    __builtin_amdgcn_s_setprio(1);                                               \
    _Pragma("unroll")                                                            \
    for (int st = 0; st < 4; ++st) {                                             \
        f32x4 z = (f32x4){0.f, 0.f, 0.f, 0.f};                                   \
        z = mfma16(*(const bf16x8*)(Ks[BUF] + ka[st * 2 + 0]), qf0, z);          \
        z = mfma16(*(const bf16x8*)(Ks[BUF] + ka[st * 2 + 1]), qf1, z);          \
        sa[st] = z;                                                              \
    }                                                                            \
    __builtin_amdgcn_s_setprio(0);                                               \
    if (MASKB) {                                                                 \
        _Pragma("unroll")                                                        \
        for (int st = 0; st < 4; ++st)                                           \
            _Pragma("unroll")                                                    \
            for (int r = 0; r < 4; ++r)                                          \
                if (st * 16 + r > dthr) sa[st][r] = -INFINITY;                   \
    }                                                                            \
    float mx = fmaxf(fmaxf(sa[0][0], sa[0][1]), sa[0][2]);                       \
    mx = fmaxf(fmaxf(mx, sa[0][3]), sa[1][0]);                                   \
    mx = fmaxf(fmaxf(mx, sa[1][1]), sa[1][2]);                                   \
    mx = fmaxf(fmaxf(mx, sa[1][3]), sa[2][0]);                                   \
    mx = fmaxf(fmaxf(mx, sa[2][1]), sa[2][2]);                                   \
    mx = fmaxf(fmaxf(mx, sa[2][3]), sa[3][0]);                                   \
    mx = fmaxf(fmaxf(mx, sa[3][1]), sa[3][2]);                                   \
    mx = fmaxf(mx, sa[3][3]);                                                    \
    mx = fmaxf(mx, __shfl_xor(mx, 16));                                          \
    mx = fmaxf(mx, __shfl_xor(mx, 32));                                          \
    float mnew = m;                                                              \
    if (!__all(mx <= m + 8.0f)) {                                                \
        mnew = fmaxf(m, mx);                                                     \
        const float rs = exp2f(m - mnew);                                        \
        m = mnew;                                                                \
        float fr[4];                                                             \
        _Pragma("unroll")                                                        \
        for (int r = 0; r < 4; ++r) fr[r] = __shfl(rs, lg * 4 + r);              \
        _Pragma("unroll")                                                        \
        for (int dt = 0; dt < 4; ++dt) {                                         \
            f32x4 ov = o[dt];                                                    \
            _Pragma("unroll")                                                    \
            for (int r = 0; r < 4; ++r) ov[r] *= fr[r];                          \
            o[dt] = ov;                                                          \
        }                                                                        \
        _Pragma("unroll")                                                        \
        for (int r = 0; r < 4; ++r) lacc[r] *= fr[r];                            \
    }                                                                            \
    _Pragma("unroll")                                                            \
    for (int st = 0; st < 4; ++st) {                                             \
        union { unsigned short u[4]; uint2 v; } pk;                              \
        _Pragma("unroll")                                                        \
        for (int r = 0; r < 4; ++r) {                                            \
            const float p = exp2f(sa[st][r] - mnew);                             \
            __hip_bfloat16 hb = __float2bfloat16(p);                             \
            pk.u[r] = *(unsigned short*)&hb;                                     \
        }                                                                        \
        *(uint2*)pw[st] = pk.v;                                                  \
    }                                                                            \
    asm volatile("s_waitcnt lgkmcnt(0)" ::: "memory");                           \
    __builtin_amdgcn_s_setprio(1);                                               \
    bf16x8 pf0 = *(const bf16x8*)pr[0];                                          \
    bf16x8 pf1 = *(const bf16x8*)pr[1];                                          \
    lacc = mfma16(pf0, ones8, lacc);                                             \
    lacc = mfma16(pf1, ones8, lacc);                                             \
    _Pragma("unroll")                                                            \
    for (int dt = 0; dt < 4; ++dt)                                               \
        o[dt] = mfma16(pf0, *(const bf16x8*)(Vs[BUF] + ka[dt * 2 + 0]), o[dt]);  \
    _Pragma("unroll")                                                            \
    for (int dt = 0; dt < 4; ++dt)                                               \
        o[dt] = mfma16(pf1, *(const bf16x8*)(Vs[BUF] + ka[dt * 2 + 1]), o[dt]);  \
    __builtin_amdgcn_s_setprio(0);                                               \
    asm volatile("s_waitcnt lgkmcnt(0)" ::: "memory");                           \
    FENCE(); __builtin_amdgcn_s_barrier(); FENCE();                              \
} while (0)

    for (int tt = 0; tt < 2; ++tt) {
        const int tile = tt ? (63 - pair) : pair;
        const int q0 = tile * 64 + wave * 16;

        bf16x8 qf0 = *(const bf16x8*)(Qh + (size_t)(q0 + l15) * DH + lg * 8);
        bf16x8 qf1 = *(const bf16x8*)(Qh + (size_t)(q0 + l15) * DH + 32 + lg * 8);

        f32x4 o[4];
#pragma unroll
        for (int dt = 0; dt < 4; ++dt) o[dt] = (f32x4){0.f, 0.f, 0.f, 0.f};
        f32x4 lacc = (f32x4){0.f, 0.f, 0.f, 0.f};  // softmax denom, rows = o rows
        float m = -1e30f;

        // per-tile global staging pointers (bumped by constants inside SBODY)
        const char* kg0 = (const char*)(Kh + (size_t)r_[0] * DH + wp_[0]);
        const char* kg1 = (const char*)(Kh + (size_t)r_[1] * DH + wp_[1]);
        const char* vg0 = (const char*)(Vh + (size_t)r_[0] * TSEQ + wp_[0]);
        const char* vg1 = (const char*)(Vh + (size_t)r_[1] * TSEQ + wp_[1]);

        const int nsb = tile + 1;
        // initial stage into buf0
        gload16(kg0, Ks[0] + wave * 1024);
        gload16(kg1, Ks[0] + 4096 + wave * 1024);
        gload16(vg0, Vs[0] + wave * 1024);
        gload16(vg1, Vs[0] + 4096 + wave * 1024);
        kg0 += 8192; kg1 += 8192; vg0 += 128; vg1 += 128;

        int sb = 0;
        while (sb + 2 <= nsb) {
            SBODY(0, true, false);
            SBODY(1, (sb + 2 < nsb), (sb + 1 == nsb - 1));
            sb += 2;
        }
        if (sb < nsb) SBODY(0, false, true);

        float inv[4];
#pragma unroll
        for (int r = 0; r < 4; ++r) inv[r] = 1.0f / lacc[r];
#pragma unroll
        for (int r = 0; r < 4; ++r) {
            const int qrow = q0 + lg * 4 + r;
            const size_t rowbase = ((size_t)b * TSEQ + qrow) * EMB + h * DH;
#pragma unroll
            for (int dt = 0; dt < 4; ++dt)
                ab[rowbase + dt * 16 + l15] = __float2bfloat16(o[dt][r] * inv[r]);
        }
    }
#undef SBODY
}

extern "C" void kernel_launch(void* const* d_in, const int* in_sizes, int n_in,
                              void* d_out, int out_size, void* d_ws, size_t ws_size,
                              hipStream_t stream) {
    (void)in_sizes; (void)n_in; (void)out_size; (void)ws_size;
    const float* x  = (const float*)d_in[0];
    const float* wq = (const float*)d_in[1];
    const float* bq = (const float*)d_in[2];
    const float* wk = (const float*)d_in[3];
    const float* bk = (const float*)d_in[4];
    const float* wv = (const float*)d_in[5];
    const float* bv = (const float*)d_in[6];
    const float* wo = (const float*)d_in[7];
    const float* bo = (const float*)d_in[8];
    float* out = (float*)d_out;

    char* ws = (char*)d_ws;
    size_t off = 0;
    auto alloc = [&](size_t bytes) {
        char* p = ws + off;
        off += (bytes + 255) & ~(size_t)255;
        return p;
    };
    __hip_bfloat16* xb  = (__hip_bfloat16*)alloc((size_t)BT * EMB * 2);
    __hip_bfloat16* qbf = (__hip_bfloat16*)alloc((size_t)BT * EMB * 2);
    __hip_bfloat16* kbf = (__hip_bfloat16*)alloc((size_t)BT * EMB * 2);
    __hip_bfloat16* vtb = (__hip_bfloat16*)alloc((size_t)BT * EMB * 2);
    __hip_bfloat16* abf = (__hip_bfloat16*)alloc((size_t)BT * EMB * 2);
    __hip_bfloat16* wqT = (__hip_bfloat16*)alloc((size_t)EMB * EMB * 2);
    __hip_bfloat16* wkT = (__hip_bfloat16*)alloc((size_t)EMB * EMB * 2);
    __hip_bfloat16* wvT = (__hip_bfloat16*)alloc((size_t)EMB * EMB * 2);
    __hip_bfloat16* woT = (__hip_bfloat16*)alloc((size_t)EMB * EMB * 2);

    conv_x_k<<<BT * EMB / 1024, 256, 0, stream>>>(x, xb);
    conv_w_k<<<dim3(24, 24, 4), 256, 0, stream>>>(wq, wk, wv, wo, wqT, wkT, wvT, woT);
    qkv_k<<<dim3(64, 6, 3), 256, 0, stream>>>(xb, wqT, wkT, wvT, bq, bk, bv, qbf, kbf, vtb);
    attn_k<<<768, 256, 0, stream>>>(qbf, kbf, vtb, abf);
    oproj_k<<<dim3(64, 6), 256, 0, stream>>>(abf, woT, bo, out);
}

// Round 7
// 198.937 us; speedup vs baseline: 3.4027x; 1.0446x over previous
//
#include <hip/hip_runtime.h>
#include <hip/hip_bf16.h>

#define TSEQ 4096
#define EMB 768
#define NH 12
#define DH 64
#define BT 8192  // B*T

typedef __attribute__((ext_vector_type(8))) short bf16x8;
typedef __attribute__((ext_vector_type(4))) float f32x4;

#define FENCE() asm volatile("" ::: "memory")

__device__ __forceinline__ f32x4 mfma16(bf16x8 a, bf16x8 b, f32x4 c) {
    return __builtin_amdgcn_mfma_f32_16x16x32_bf16(a, b, c, 0, 0, 0);
}

__device__ __forceinline__ void gload16(const void* g, void* l) {
    __builtin_amdgcn_global_load_lds((const __attribute__((address_space(1))) void*)g,
                                     (__attribute__((address_space(3))) void*)l, 16, 0, 0);
}

// ---------- conversion kernels ----------
__global__ __launch_bounds__(256) void conv_x_k(const float* __restrict__ x,
                                                __hip_bfloat16* __restrict__ xb) {
    int i = (blockIdx.x * 256 + threadIdx.x) * 4;
    float4 v = *(const float4*)(x + i);
    union { unsigned short u[4]; uint2 p; } o;
    __hip_bfloat16 t0 = __float2bfloat16(v.x); o.u[0] = *(unsigned short*)&t0;
    __hip_bfloat16 t1 = __float2bfloat16(v.y); o.u[1] = *(unsigned short*)&t1;
    __hip_bfloat16 t2 = __float2bfloat16(v.z); o.u[2] = *(unsigned short*)&t2;
    __hip_bfloat16 t3 = __float2bfloat16(v.w); o.u[3] = *(unsigned short*)&t3;
    *(uint2*)(xb + i) = o.p;
}

// transpose 768x768 fp32 (k,n) -> bf16 (n,k); z selects which weight
__global__ __launch_bounds__(256) void conv_w_k(const float* w0, const float* w1,
                                                const float* w2, const float* w3,
                                                __hip_bfloat16* o0, __hip_bfloat16* o1,
                                                __hip_bfloat16* o2, __hip_bfloat16* o3) {
    const float* w; __hip_bfloat16* o;
    switch (blockIdx.z) {
        case 0: w = w0; o = o0; break;
        case 1: w = w1; o = o1; break;
        case 2: w = w2; o = o2; break;
        default: w = w3; o = o3; break;
    }
    __shared__ float tile[32][33];
    int tx = threadIdx.x & 31, ty = threadIdx.x >> 5;  // 32 x 8
    int kb = blockIdx.y * 32, nb = blockIdx.x * 32;
    for (int i = 0; i < 32; i += 8)
        tile[ty + i][tx] = w[(size_t)(kb + ty + i) * EMB + nb + tx];
    __syncthreads();
    for (int i = 0; i < 32; i += 8)
        o[(size_t)(nb + ty + i) * EMB + kb + tx] = __float2bfloat16(tile[tx][ty + i]);
}

// ---------- GEMM body: C(M,N) = scale * (A(M,K) * Wt(N,K)^T + bias) ----------
__device__ __forceinline__ void gemm_body(const __hip_bfloat16* __restrict__ A,
                                          const __hip_bfloat16* __restrict__ Wt,
                                          const float* __restrict__ bias,
                                          void* __restrict__ outp, int mode, float scale) {
    __shared__ alignas(16) char As[2][8192];
    __shared__ alignas(16) char Bs[2][8192];
    const int m0 = blockIdx.x * 128, n0 = blockIdx.y * 128;
    const int tid = threadIdx.x;
    const int lane = tid & 63, l15 = lane & 15, lg = lane >> 4;
    const int wave = tid >> 6, wm = wave >> 1, wn = wave & 1;
    const int swz = (l15 & 7) << 4;

    int mrow_[2]; int kelem_[2];
#pragma unroll
    for (int c = 0; c < 2; ++c) {
        int p = c * 4096 + tid * 16;
        int lrow = p >> 7, w = p & 127;
        int wp = w ^ ((lrow & 7) << 4);
        mrow_[c] = lrow + ((wp >> 6) & 1) * 64;
        kelem_[c] = (wp & 63) >> 1;
    }

    f32x4 acc[4][4];
    for (int i = 0; i < 4; ++i)
        for (int j = 0; j < 4; ++j) acc[i][j] = (f32x4){0.f, 0.f, 0.f, 0.f};

    auto stage = [&](int buf, int k0) {
#pragma unroll
        for (int c = 0; c < 2; ++c)
            gload16(A + (size_t)(m0 + mrow_[c]) * EMB + k0 + kelem_[c],
                    As[buf] + c * 4096 + wave * 1024);
#pragma unroll
        for (int c = 0; c < 2; ++c)
            gload16(Wt + (size_t)(n0 + mrow_[c]) * EMB + k0 + kelem_[c],
                    Bs[buf] + c * 4096 + wave * 1024);
    };

    stage(0, 0);
    const int NK = EMB / 32;
    for (int ks = 0; ks < NK; ++ks) {
        const int cur = ks & 1;
        const bool pre = (ks + 1 < NK);
        if (pre) stage(cur ^ 1, (ks + 1) * 32);
        if (pre) asm volatile("s_waitcnt vmcnt(4)" ::: "memory");
        else     asm volatile("s_waitcnt vmcnt(0)" ::: "memory");
        FENCE(); __builtin_amdgcn_s_barrier(); FENCE();
        bf16x8 af[4], bfv[4];
#pragma unroll
        for (int f = 0; f < 4; ++f)
            af[f] = *(const bf16x8*)(As[cur] + (f * 16 + l15) * 128 + ((wm * 64 + lg * 16) ^ swz));
#pragma unroll
        for (int f = 0; f < 4; ++f)
            bfv[f] = *(const bf16x8*)(Bs[cur] + (f * 16 + l15) * 128 + ((wn * 64 + lg * 16) ^ swz));
        __builtin_amdgcn_s_setprio(1);
#pragma unroll
        for (int i = 0; i < 4; ++i)
#pragma unroll
            for (int j = 0; j < 4; ++j)
                acc[i][j] = mfma16(af[i], bfv[j], acc[i][j]);
        __builtin_amdgcn_s_setprio(0);
        FENCE(); __builtin_amdgcn_s_barrier(); FENCE();
    }

#pragma unroll
    for (int i = 0; i < 4; ++i) {
#pragma unroll
        for (int j = 0; j < 4; ++j) {
            const int n = n0 + wn * 64 + j * 16 + l15;
            const float bv = bias[n];
            const int mbase = m0 + wm * 64 + i * 16 + lg * 4;
#pragma unroll
            for (int r = 0; r < 4; ++r) {
                const int m = mbase + r;
                const float val = (acc[i][j][r] + bv) * scale;
                if (mode == 2) {
                    ((float*)outp)[(size_t)m * EMB + n] = val;
                } else {
                    const int b = m >> 12, t = m & (TSEQ - 1);
                    const int h = n >> 6, d = n & 63;
                    size_t addr;
                    if (mode == 0) addr = ((size_t)(b * NH + h) * TSEQ + t) * DH + d;
                    else           addr = ((size_t)(b * NH + h) * DH + d) * TSEQ + t;
                    ((__hip_bfloat16*)outp)[addr] = __float2bfloat16(val);
                }
            }
        }
    }
}

__global__ __launch_bounds__(256) void qkv_k(const __hip_bfloat16* __restrict__ xb,
                                             const __hip_bfloat16* __restrict__ wqT,
                                             const __hip_bfloat16* __restrict__ wkT,
                                             const __hip_bfloat16* __restrict__ wvT,
                                             const float* __restrict__ bq,
                                             const float* __restrict__ bk,
                                             const float* __restrict__ bv,
                                             __hip_bfloat16* __restrict__ qo,
                                             __hip_bfloat16* __restrict__ ko,
                                             __hip_bfloat16* __restrict__ vo) {
    const __hip_bfloat16* Wt; const float* bias; void* o; int mode; float scale;
    const float cq = 0.125f * 1.44269504089f;  // softmax scale * log2(e), folded into Q
    switch (blockIdx.z) {
        case 0:  Wt = wqT; bias = bq; o = qo; mode = 0; scale = cq;  break;
        case 1:  Wt = wkT; bias = bk; o = ko; mode = 0; scale = 1.f; break;
        default: Wt = wvT; bias = bv; o = vo; mode = 1; scale = 1.f; break;
    }
    gemm_body(xb, Wt, bias, o, mode, scale);
}

__global__ __launch_bounds__(256) void oproj_k(const __hip_bfloat16* __restrict__ abf,
                                               const __hip_bfloat16* __restrict__ woT,
                                               const float* __restrict__ bo,
                                               float* __restrict__ out) {
    gemm_body(abf, woT, bo, out, 2, 1.f);
}

// ---------- flash attention ----------
// Q (pre-scaled by 0.125*log2e), K: (B,H,T,D) bf16. V: (B,H,D,T) bf16.
// Block = 4 waves; each wave owns TWO 16-row q-tiles: lo = pair, hi = 63-pair,
// processed in ONE s-block sweep (sb = 0..63-pair); lo active while sb <= pair.
// Per wave: 65 tile-units (balanced), but only 64-pair staged iterations.
// ONE barrier per s-block: vmcnt(0) BEFORE barrier, stage-issue AFTER barrier
// (all waves provably done reading the victim buffer). Per-wave P bounce uses
// in-order DS semantics: single lgkmcnt(0) between P-write and P-read.
__global__ __launch_bounds__(256, 3) void attn_k(const __hip_bfloat16* __restrict__ qb,
                                                 const __hip_bfloat16* __restrict__ kb,
                                                 const __hip_bfloat16* __restrict__ vt,
                                                 __hip_bfloat16* __restrict__ ab) {
    __shared__ alignas(16) char Ks[2][8192];
    __shared__ alignas(16) char Vs[2][8192];
    __shared__ alignas(16) char pbuf[4][2048];  // per-wave P bounce, swizzled
    const int lane = threadIdx.x & 63, l15 = lane & 15, lg = lane >> 4;
    const int wave = threadIdx.x >> 6;
    const int bid = blockIdx.x;
    const int xcd = bid & 7, slot = bid >> 3;
    const int pair = slot & 31, hgrp = slot >> 5;
    const int bh = xcd + hgrp * 8;           // head-clustered XCD mapping
    const __hip_bfloat16* Qh = qb + (size_t)bh * TSEQ * DH;
    const __hip_bfloat16* Kh = kb + (size_t)bh * TSEQ * DH;
    const __hip_bfloat16* Vh = vt + (size_t)bh * DH * TSEQ;
    char* Pb = pbuf[wave];
    const int swz = (l15 & 7) << 4;
    const int b = bh / NH, h = bh % NH;

    bf16x8 ones8;
#pragma unroll
    for (int j = 0; j < 8; ++j) ones8[j] = (short)0x3F80;  // bf16 1.0

    // hoisted loop-invariant LDS addresses
    unsigned ka[8];
#pragma unroll
    for (int st = 0; st < 4; ++st)
#pragma unroll
        for (int ks = 0; ks < 2; ++ks)
            ka[st * 2 + ks] = (unsigned)((st * 16 + l15) * 128 + ((ks * 64 + lg * 16) ^ swz));
    char* pw[4]; char* pr[2];
#pragma unroll
    for (int st = 0; st < 4; ++st) pw[st] = Pb + l15 * 128 + ((st * 32 + lg * 8) ^ swz);
#pragma unroll
    for (int ks = 0; ks < 2; ++ks) pr[ks] = Pb + l15 * 128 + ((ks * 64 + lg * 16) ^ swz);
    const int dthr = wave * 16 + l15 - lg * 4;  // mask when st*16 + r > dthr

    // staging geometry: chunk c: linear p = c*4096 + wave*1024 + lane*16
    int r_[2], wp_[2];
#pragma unroll
    for (int c = 0; c < 2; ++c) {
        int p = c * 4096 + wave * 1024 + lane * 16;
        int r = p >> 7, w = p & 127;
        r_[c] = r;
        wp_[c] = (w ^ ((r & 7) << 4)) >> 1;
    }

    const int lo = pair, hi = 63 - pair;
    const int q0l = lo * 64 + wave * 16;
    const int q0h = hi * 64 + wave * 16;
    const int nsb = hi + 1;

    // Q fragments for both tiles
    bf16x8 qh0 = *(const bf16x8*)(Qh + (size_t)(q0h + l15) * DH + lg * 8);
    bf16x8 qh1 = *(const bf16x8*)(Qh + (size_t)(q0h + l15) * DH + 32 + lg * 8);
    bf16x8 ql0 = *(const bf16x8*)(Qh + (size_t)(q0l + l15) * DH + lg * 8);
    bf16x8 ql1 = *(const bf16x8*)(Qh + (size_t)(q0l + l15) * DH + 32 + lg * 8);

    f32x4 oh[4], ol[4];
#pragma unroll
    for (int dt = 0; dt < 4; ++dt) { oh[dt] = (f32x4){0.f,0.f,0.f,0.f}; ol[dt] = (f32x4){0.f,0.f,0.f,0.f}; }
    f32x4 lh = (f32x4){0.f,0.f,0.f,0.f}, ll = (f32x4){0.f,0.f,0.f,0.f};
    float mh = -1e30f, ml = -1e30f;

    // global staging pointers
    const char* kg0 = (const char*)(Kh + (size_t)r_[0] * DH + wp_[0]);
    const char* kg1 = (const char*)(Kh + (size_t)r_[1] * DH + wp_[1]);
    const char* vg0 = (const char*)(Vh + (size_t)r_[0] * TSEQ + wp_[0]);
    const char* vg1 = (const char*)(Vh + (size_t)r_[1] * TSEQ + wp_[1]);

#define STAGE(DST) do {                                                          \
    gload16(kg0, Ks[DST] + wave * 1024);                                         \
    gload16(kg1, Ks[DST] + 4096 + wave * 1024);                                  \
    gload16(vg0, Vs[DST] + wave * 1024);                                         \
    gload16(vg1, Vs[DST] + 4096 + wave * 1024);                                  \
    kg0 += 8192; kg1 += 8192; vg0 += 128; vg1 += 128;                            \
} while (0)

#define TUNIT(BUF, Q0, Q1, OV, LA, MM, MASKB) do {                               \
    f32x4 sa[4];                                                                 \
    __builtin_amdgcn_s_setprio(1);                                               \
    _Pragma("unroll")                                                            \
    for (int st = 0; st < 4; ++st) {                                             \
        f32x4 z = (f32x4){0.f, 0.f, 0.f, 0.f};                                   \
        z = mfma16(*(const bf16x8*)(Ks[BUF] + ka[st * 2 + 0]), Q0, z);           \
        z = mfma16(*(const bf16x8*)(Ks[BUF] + ka[st * 2 + 1]), Q1, z);           \
        sa[st] = z;                                                              \
    }                                                                            \
    __builtin_amdgcn_s_setprio(0);                                               \
    if (MASKB) {                                                                 \
        _Pragma("unroll")                                                        \
        for (int st = 0; st < 4; ++st)                                           \
            _Pragma("unroll")                                                    \
            for (int r = 0; r < 4; ++r)                                          \
                if (st * 16 + r > dthr) sa[st][r] = -INFINITY;                   \
    }                                                                            \
    float mx = fmaxf(fmaxf(sa[0][0], sa[0][1]), sa[0][2]);                       \
    mx = fmaxf(fmaxf(mx, sa[0][3]), sa[1][0]);                                   \
    mx = fmaxf(fmaxf(mx, sa[1][1]), sa[1][2]);                                   \
    mx = fmaxf(fmaxf(mx, sa[1][3]), sa[2][0]);                                   \
    mx = fmaxf(fmaxf(mx, sa[2][1]), sa[2][2]);                                   \
    mx = fmaxf(fmaxf(mx, sa[2][3]), sa[3][0]);                                   \
    mx = fmaxf(fmaxf(mx, sa[3][1]), sa[3][2]);                                   \
    mx = fmaxf(mx, sa[3][3]);                                                    \
    mx = fmaxf(mx, __shfl_xor(mx, 16));                                          \
    mx = fmaxf(mx, __shfl_xor(mx, 32));                                          \
    float mnew = MM;                                                             \
    if (!__all(mx <= MM + 8.0f)) {                                               \
        mnew = fmaxf(MM, mx);                                                    \
        const float rs = exp2f(MM - mnew);                                       \
        MM = mnew;                                                               \
        float fr[4];                                                             \
        _Pragma("unroll")                                                        \
        for (int r = 0; r < 4; ++r) fr[r] = __shfl(rs, lg * 4 + r);              \
        _Pragma("unroll")                                                        \
        for (int dt = 0; dt < 4; ++dt) {                                         \
            f32x4 ov = OV[dt];                                                   \
            _Pragma("unroll")                                                    \
            for (int r = 0; r < 4; ++r) ov[r] *= fr[r];                          \
            OV[dt] = ov;                                                         \
        }                                                                        \
        _Pragma("unroll")                                                        \
        for (int r = 0; r < 4; ++r) LA[r] *= fr[r];                              \
    }                                                                            \
    _Pragma("unroll")                                                            \
    for (int st = 0; st < 4; ++st) {                                             \
        union { unsigned short u[4]; uint2 v; } pk;                              \
        _Pragma("unroll")                                                        \
        for (int r = 0; r < 4; ++r) {                                            \
            const float p = exp2f(sa[st][r] - mnew);                             \
            __hip_bfloat16 hb = __float2bfloat16(p);                             \
            pk.u[r] = *(unsigned short*)&hb;                                     \
        }                                                                        \
        *(uint2*)pw[st] = pk.v;                                                  \
    }                                                                            \
    asm volatile("s_waitcnt lgkmcnt(0)" ::: "memory");                           \
    bf16x8 pf0 = *(const bf16x8*)pr[0];                                          \
    bf16x8 pf1 = *(const bf16x8*)pr[1];                                          \
    __builtin_amdgcn_s_setprio(1);                                               \
    LA = mfma16(pf0, ones8, LA);                                                 \
    LA = mfma16(pf1, ones8, LA);                                                 \
    _Pragma("unroll")                                                            \
    for (int dt = 0; dt < 4; ++dt)                                               \
        OV[dt] = mfma16(pf0, *(const bf16x8*)(Vs[BUF] + ka[dt * 2 + 0]), OV[dt]);\
    _Pragma("unroll")                                                            \
    for (int dt = 0; dt < 4; ++dt)                                               \
        OV[dt] = mfma16(pf1, *(const bf16x8*)(Vs[BUF] + ka[dt * 2 + 1]), OV[dt]);\
    __builtin_amdgcn_s_setprio(0);                                               \
} while (0)

#define SBODY(BUF, PRE, LOACT, MHI, MLO) do {                                    \
    asm volatile("s_waitcnt vmcnt(0)" ::: "memory");                             \
    FENCE(); __builtin_amdgcn_s_barrier(); FENCE();                              \
    if (PRE) STAGE((BUF) ^ 1);                                                   \
    TUNIT(BUF, qh0, qh1, oh, lh, mh, MHI);                                       \
    if (LOACT) TUNIT(BUF, ql0, ql1, ol, ll, ml, MLO);                            \
} while (0)

    STAGE(0);  // initial stage into buf0
    int sb = 0;
    while (sb + 2 <= nsb) {
        SBODY(0, true, sb <= lo, false, sb == lo);
        SBODY(1, sb + 2 < nsb, sb + 1 <= lo, sb + 1 == nsb - 1, sb + 1 == lo);
        sb += 2;
    }
    if (sb < nsb) SBODY(0, false, sb <= lo, true, sb == lo);

#undef SBODY
#undef TUNIT
#undef STAGE

    // ---- write both tiles ----
    {
        float inv[4];
#pragma unroll
        for (int r = 0; r < 4; ++r) inv[r] = 1.0f / lh[r];
#pragma unroll
        for (int r = 0; r < 4; ++r) {
            const int qrow = q0h + lg * 4 + r;
            const size_t rowbase = ((size_t)b * TSEQ + qrow) * EMB + h * DH;
#pragma unroll
            for (int dt = 0; dt < 4; ++dt)
                ab[rowbase + dt * 16 + l15] = __float2bfloat16(oh[dt][r] * inv[r]);
        }
    }
    {
        float inv[4];
#pragma unroll
        for (int r = 0; r < 4; ++r) inv[r] = 1.0f / ll[r];
#pragma unroll
        for (int r = 0; r < 4; ++r) {
            const int qrow = q0l + lg * 4 + r;
            const size_t rowbase = ((size_t)b * TSEQ + qrow) * EMB + h * DH;
#pragma unroll
            for (int dt = 0; dt < 4; ++dt)
                ab[rowbase + dt * 16 + l15] = __float2bfloat16(ol[dt][r] * inv[r]);
        }
    }
}

extern "C" void kernel_launch(void* const* d_in, const int* in_sizes, int n_in,
                              void* d_out, int out_size, void* d_ws, size_t ws_size,
                              hipStream_t stream) {
    (void)in_sizes; (void)n_in; (void)out_size; (void)ws_size;
    const float* x  = (const float*)d_in[0];
    const float* wq = (const float*)d_in[1];
    const float* bq = (const float*)d_in[2];
    const float* wk = (const float*)d_in[3];
    const float* bk = (const float*)d_in[4];
    const float* wv = (const float*)d_in[5];
    const float* bv = (const float*)d_in[6];
    const float* wo = (const float*)d_in[7];
    const float* bo = (const float*)d_in[8];
    float* out = (float*)d_out;

    char* ws = (char*)d_ws;
    size_t off = 0;
    auto alloc = [&](size_t bytes) {
        char* p = ws + off;
        off += (bytes + 255) & ~(size_t)255;
        return p;
    };
    __hip_bfloat16* xb  = (__hip_bfloat16*)alloc((size_t)BT * EMB * 2);
    __hip_bfloat16* qbf = (__hip_bfloat16*)alloc((size_t)BT * EMB * 2);
    __hip_bfloat16* kbf = (__hip_bfloat16*)alloc((size_t)BT * EMB * 2);
    __hip_bfloat16* vtb = (__hip_bfloat16*)alloc((size_t)BT * EMB * 2);
    __hip_bfloat16* abf = (__hip_bfloat16*)alloc((size_t)BT * EMB * 2);
    __hip_bfloat16* wqT = (__hip_bfloat16*)alloc((size_t)EMB * EMB * 2);
    __hip_bfloat16* wkT = (__hip_bfloat16*)alloc((size_t)EMB * EMB * 2);
    __hip_bfloat16* wvT = (__hip_bfloat16*)alloc((size_t)EMB * EMB * 2);
    __hip_bfloat16* woT = (__hip_bfloat16*)alloc((size_t)EMB * EMB * 2);

    conv_x_k<<<BT * EMB / 1024, 256, 0, stream>>>(x, xb);
    conv_w_k<<<dim3(24, 24, 4), 256, 0, stream>>>(wq, wk, wv, wo, wqT, wkT, wvT, woT);
    qkv_k<<<dim3(64, 6, 3), 256, 0, stream>>>(xb, wqT, wkT, wvT, bq, bk, bv, qbf, kbf, vtb);
    attn_k<<<768, 256, 0, stream>>>(qbf, kbf, vtb, abf);
    oproj_k<<<dim3(64, 6), 256, 0, stream>>>(abf, woT, bo, out);
}